// Round 1
// baseline (315.095 us; speedup 1.0000x reference)
//
#include <hip/hip_runtime.h>
#include <math.h>

#define SEQ   8192
#define DIM   2048
#define NH    16
#define DH    128
#define PD    512
#define NBLK  256
#define NTHR  512

static constexpr float LN_EPS = 1e-5f;
static constexpr float SCALE  = 0.08838834764831845f; // 1/sqrt(128)

typedef __bf16 bf16x8 __attribute__((ext_vector_type(8)));
typedef float  f32x4  __attribute__((ext_vector_type(4)));

// ---- workspace layout (floats); all offsets 16B aligned ----
static constexpr size_t OFF_QB   = 0;                    // 16
static constexpr size_t OFF_SMP  = 16;                   // 512 = smp[h][32]
static constexpr size_t OFF_QWB  = 528;                  // 16*2048 bf16 = 16384 floats
static constexpr size_t OFF_PCTX = 16912;                // 256*16*2048 = 8388608
static constexpr size_t OFF_CTX  = OFF_PCTX + 8388608;   // 32768
static constexpr size_t OFF_X1   = OFF_CTX + 32768;      // 2048
static constexpr size_t OFF_H1R  = OFF_X1 + 2048;        // 512
static constexpr size_t OFF_X1F  = OFF_H1R + 512;        // 2048
static constexpr size_t OFF_BAR  = OFF_X1F + 2048;       // 8 uints (barrier counters)

// Device-scope grid barrier. Safe: 256 blocks x 512thr, VGPR<=256 (launch_bounds)
// => capacity >= 1 block/CU on 256 CUs => all blocks resident under any dispatch
// order. Counters zeroed by k_init each call (ws is re-poisoned by harness).
// Spin is iteration-capped so a logic bug fails absmax instead of hanging.
__device__ __forceinline__ void gsync(unsigned int* bar) {
    __syncthreads();
    if (threadIdx.x == 0) {
        __threadfence();                       // agent-scope release (wb L2)
        atomicAdd(bar, 1u);
        for (unsigned int it = 0; it < (1u << 21); ++it) {
            unsigned int v = __hip_atomic_load(bar, __ATOMIC_ACQUIRE,
                                               __HIP_MEMORY_SCOPE_AGENT);
            if (v >= (unsigned int)NBLK) break;
            __builtin_amdgcn_s_sleep(2);
        }
    }
    __syncthreads();
}

__global__ __launch_bounds__(512) void k_init(float* smp, unsigned int* bars) {
    smp[threadIdx.x] = 0.f;                    // 512 = 16 heads x 32 slots
    if (threadIdx.x < 8) bars[threadIdx.x] = 0u;
}

__global__ __launch_bounds__(NTHR, 2) void k_mega(
    const float* __restrict__ x,   const float* __restrict__ q,
    const float* __restrict__ Wkv, const float* __restrict__ bkv,
    const float* __restrict__ Wp1, const float* __restrict__ bp1,
    const float* __restrict__ Wp2, const float* __restrict__ bp2,
    const float* __restrict__ lnw, const float* __restrict__ lnb,
    float* __restrict__ out, float* __restrict__ ws)
{
    const int b = blockIdx.x, t = threadIdx.x;
    const int w8 = t >> 6, lane = t & 63;

    float*        qb    = ws + OFF_QB;
    float*        smp   = ws + OFF_SMP;
    __bf16*       qWb   = (__bf16*)(ws + OFF_QWB);
    float*        pctx  = ws + OFF_PCTX;
    float*        ctx   = ws + OFF_CTX;
    float*        x1    = ws + OFF_X1;
    float*        h1raw = ws + OFF_H1R;
    float*        x1f   = ws + OFF_X1F;
    unsigned int* bars  = (unsigned int*)(ws + OFF_BAR);

    __shared__ float part[4][128];
    __shared__ float qred[8];
    __shared__ float dpart[2][4][64][4];
    __shared__ float att[32][NH];
    __shared__ float hsum[NH];
    __shared__ float psum[4][128];
    __shared__ float sInv;

    // ================= P0: prep  qWb[h][j]=q_h·W_k[:,j] (bf16), qb[h]=q_h·b_k =================
    {
        const int h = b >> 4, jc = b & 15;
        const int col = t & 127, kh = t >> 7;          // 4 k-groups of 32 d's
        const int j = jc * 128 + col;
        const float* w  = Wkv + (size_t)(h * DH + kh * 32) * DIM + j;
        const float* qh = q + h * DH + kh * 32;
        float acc = 0.f;
#pragma unroll
        for (int d = 0; d < 32; ++d)
            acc += qh[d] * w[(size_t)d * DIM];
        part[kh][col] = acc;
        __syncthreads();
        if (kh == 0)
            qWb[h * DIM + j] = (__bf16)(part[0][col] + part[1][col]
                                      + part[2][col] + part[3][col]);
        if (jc == 0) {                                  // block-uniform branch
            float p = (t < DH) ? q[h * DH + t] * bkv[h * DH + t] : 0.f;
            for (int off = 32; off; off >>= 1) p += __shfl_xor(p, off);
            if (lane == 0) qred[w8] = p;
            __syncthreads();
            if (t == 0) {
                float s = 0.f;
#pragma unroll
                for (int i = 0; i < 8; ++i) s += qred[i];
                qb[h] = s;
            }
        }
    }
    gsync(bars + 0);

    // ================= P1: fused logits (MFMA) + unnormalized weighted ctx partials =========
    {
        const int s0 = b * 32;
        const int rg = w8 & 1, kq = w8 >> 1;            // 2 row-groups x 4 K-quarters
        const int r = lane & 15, quad = lane >> 4;
        if (t < NH) hsum[t] = 0.f;

        const float*  xrow = x + (size_t)(s0 + rg * 16 + r) * DIM + quad * 8;
        const __bf16* brow = qWb + r * DIM + quad * 8;  // r doubles as h for B operand
        const int kbase = kq * 512;
        f32x4 acc = {0.f, 0.f, 0.f, 0.f};
#pragma unroll 4
        for (int i = 0; i < 16; ++i) {
            int k = kbase + i * 32;
            float4 xa  = *(const float4*)(xrow + k);
            float4 xb2 = *(const float4*)(xrow + k + 4);
            bf16x8 af;
            af[0] = (__bf16)xa.x;  af[1] = (__bf16)xa.y;
            af[2] = (__bf16)xa.z;  af[3] = (__bf16)xa.w;
            af[4] = (__bf16)xb2.x; af[5] = (__bf16)xb2.y;
            af[6] = (__bf16)xb2.z; af[7] = (__bf16)xb2.w;
            bf16x8 bfv = *(const bf16x8*)(brow + k);
            acc = __builtin_amdgcn_mfma_f32_16x16x32_bf16(af, bfv, acc, 0, 0, 0);
        }
        *(f32x4*)&dpart[rg][kq][lane][0] = acc;
        __syncthreads();

        {   // combine K-quarters -> e = exp((logit+qb)*scale); |logit| <~ 5, no max-sub
            const int h = t & 15, slp = t >> 4;         // slp: 0..31 local row
            const int rg2 = slp >> 4, sli = slp & 15;
            const int quad2 = sli >> 2, reg2 = sli & 3;
            const int lane2 = quad2 * 16 + h;
            float v = dpart[rg2][0][lane2][reg2] + dpart[rg2][1][lane2][reg2]
                    + dpart[rg2][2][lane2][reg2] + dpart[rg2][3][lane2][reg2];
            float e = __expf((v + qb[h]) * SCALE);
            att[slp][h] = e;
            atomicAdd(&hsum[h], e);
        }
        __syncthreads();
        if (t < NH) atomicAdd(&smp[t * 32 + (b & 31)], hsum[t]);

        // phase B: pctx[b][h][j0..j0+4) = sum_rr e[rr][h] * x[s0+rr][j0..j0+4)
        // x rows are L2/L3-hot (just streamed by this block's MFMA phase).
        const int j0 = t * 4;
        f32x4 zero = {0.f, 0.f, 0.f, 0.f};
        f32x4 acc4[NH];
#pragma unroll
        for (int h = 0; h < NH; ++h) acc4[h] = zero;
#pragma unroll 2
        for (int rr = 0; rr < 32; ++rr) {
            f32x4 xv = *(const f32x4*)(x + (size_t)(s0 + rr) * DIM + j0);
            const f32x4* ar = (const f32x4*)att[rr];    // LDS broadcast reads
            f32x4 a0 = ar[0], a1 = ar[1], a2 = ar[2], a3 = ar[3];
            float aa[16];
            *(f32x4*)&aa[0] = a0; *(f32x4*)&aa[4]  = a1;
            *(f32x4*)&aa[8] = a2; *(f32x4*)&aa[12] = a3;
#pragma unroll
            for (int h = 0; h < NH; ++h) acc4[h] += xv * aa[h];
        }
#pragma unroll
        for (int h = 0; h < NH; ++h)
            *(f32x4*)&pctx[((size_t)(b * NH + h)) * DIM + j0] = acc4[h];
    }
    gsync(bars + 1);

    // ================= P2: reduce 256 chunks + softmax normalize =================
    {
        const int h = b >> 4;                           // 128 ctx elems/block, single head
        float v = (t < 32) ? smp[h * 32 + t] : 0.f;
        if (t < 64) {
            for (int off = 16; off; off >>= 1) v += __shfl_xor(v, off);
            if (t == 0) sInv = 1.f / v;
        }
        const int tg = t >> 7, tt = t & 127;
        const size_t idx = (size_t)b * 128 + tt;        // global ctx index
        const int c0 = tg * 64;
        float s = 0.f;
#pragma unroll 8
        for (int c = 0; c < 64; ++c)
            s += pctx[(size_t)(c0 + c) * (NH * DIM) + idx];
        psum[tg][tt] = s;
        __syncthreads();
        if (tg == 0)
            ctx[idx] = (psum[0][tt] + psum[1][tt] + psum[2][tt] + psum[3][tt]) * sInv;
    }
    gsync(bars + 2);

    // ================= P3: x1[row] = ctx[row>>7]·W_v[row] + b_v[row] =================
    {
        const int row = b * 8 + w8;                     // 2048 rows, 1/wave
        const float* wv = Wkv + (size_t)(DIM + row) * DIM;
        const float* cc = ctx + (size_t)(row >> 7) * DIM;
        float acc = 0.f;
#pragma unroll
        for (int i = 0; i < 8; ++i) {
            int j = i * 256 + lane * 4;
            f32x4 a  = *(const f32x4*)(wv + j);
            f32x4 c2 = *(const f32x4*)(cc + j);
            acc += a[0]*c2[0] + a[1]*c2[1] + a[2]*c2[2] + a[3]*c2[3];
        }
        for (int off = 32; off; off >>= 1) acc += __shfl_xor(acc, off);
        if (lane == 0) x1[row] = acc + bkv[DIM + row];
    }
    gsync(bars + 3);

    // ================= P4: h1raw[row] = x1·W_p1[row] + b_p1[row] =================
    if (w8 < 2) {                                       // 512 rows, 2/block
        const int row = b * 2 + w8;
        const float* wv = Wp1 + (size_t)row * DIM;
        float acc = 0.f;
#pragma unroll
        for (int i = 0; i < 8; ++i) {
            int j = i * 256 + lane * 4;
            f32x4 a  = *(const f32x4*)(wv + j);
            f32x4 c2 = *(const f32x4*)(x1 + j);
            acc += a[0]*c2[0] + a[1]*c2[1] + a[2]*c2[2] + a[3]*c2[3];
        }
        for (int off = 32; off; off >>= 1) acc += __shfl_xor(acc, off);
        if (lane == 0) h1raw[row] = acc + bp1[row];
    }
    gsync(bars + 4);

    // ================= P5: x1f[row] = relu(LN(h1raw))·W_p2[row] + b_p2[row] =================
    {
        const int row = b * 8 + w8;                     // 2048 rows, 1/wave
        const int j = lane * 8;
        f32x4 va  = *(const f32x4*)(h1raw + j);
        f32x4 vb2 = *(const f32x4*)(h1raw + j + 4);
        float s = va[0]+va[1]+va[2]+va[3]+vb2[0]+vb2[1]+vb2[2]+vb2[3];
        for (int off = 32; off; off >>= 1) s += __shfl_xor(s, off);
        float mu = s * (1.0f / PD);
        float dx[8];
        dx[0]=va[0]-mu;  dx[1]=va[1]-mu;  dx[2]=va[2]-mu;  dx[3]=va[3]-mu;
        dx[4]=vb2[0]-mu; dx[5]=vb2[1]-mu; dx[6]=vb2[2]-mu; dx[7]=vb2[3]-mu;
        float s2 = 0.f;
#pragma unroll
        for (int i = 0; i < 8; ++i) s2 += dx[i] * dx[i];
        for (int off = 32; off; off >>= 1) s2 += __shfl_xor(s2, off);
        float rstd = rsqrtf(s2 * (1.0f / PD) + LN_EPS);
        f32x4 lw0 = *(const f32x4*)(lnw + j), lw1 = *(const f32x4*)(lnw + j + 4);
        f32x4 lb0 = *(const f32x4*)(lnb + j), lb1 = *(const f32x4*)(lnb + j + 4);
        float hln[8];
        hln[0]=fmaxf(dx[0]*rstd*lw0[0]+lb0[0],0.f); hln[1]=fmaxf(dx[1]*rstd*lw0[1]+lb0[1],0.f);
        hln[2]=fmaxf(dx[2]*rstd*lw0[2]+lb0[2],0.f); hln[3]=fmaxf(dx[3]*rstd*lw0[3]+lb0[3],0.f);
        hln[4]=fmaxf(dx[4]*rstd*lw1[0]+lb1[0],0.f); hln[5]=fmaxf(dx[5]*rstd*lw1[1]+lb1[1],0.f);
        hln[6]=fmaxf(dx[6]*rstd*lw1[2]+lb1[2],0.f); hln[7]=fmaxf(dx[7]*rstd*lw1[3]+lb1[3],0.f);
        const float* w = Wp2 + (size_t)row * PD + j;
        f32x4 w0 = *(const f32x4*)w, w1 = *(const f32x4*)(w + 4);
        float acc = w0[0]*hln[0] + w0[1]*hln[1] + w0[2]*hln[2] + w0[3]*hln[3]
                  + w1[0]*hln[4] + w1[1]*hln[5] + w1[2]*hln[6] + w1[3]*hln[7];
        for (int off = 32; off; off >>= 1) acc += __shfl_xor(acc, off);
        if (lane == 0) x1f[row] = acc + bp2[row];
    }
    gsync(bars + 5);

    // ================= P6: out = x + broadcast(x1f) =================
    {
        const f32x4* x4 = (const f32x4*)x;
        f32x4*       o4 = (f32x4*)out;
        const f32x4  add = ((const f32x4*)x1f)[t];      // (i & 511) == t for all iters
        const size_t base = (size_t)b * NTHR + t;
#pragma unroll 8
        for (int k2 = 0; k2 < 32; ++k2) {
            size_t i = (size_t)k2 * (NBLK * NTHR) + base;
            o4[i] = x4[i] + add;
        }
    }
}

extern "C" void kernel_launch(void* const* d_in, const int* in_sizes, int n_in,
                              void* d_out, int out_size, void* d_ws, size_t ws_size,
                              hipStream_t stream) {
    const float* x    = (const float*)d_in[0];
    const float* q    = (const float*)d_in[1];
    const float* Wkv  = (const float*)d_in[2];
    const float* bkv  = (const float*)d_in[3];
    const float* Wp1  = (const float*)d_in[4];
    const float* bp1  = (const float*)d_in[5];
    const float* Wp2  = (const float*)d_in[6];
    const float* bp2  = (const float*)d_in[7];
    const float* lnw  = (const float*)d_in[8];
    const float* lnb  = (const float*)d_in[9];
    float* ws = (float*)d_ws;

    k_init<<<1, 512, 0, stream>>>(ws + OFF_SMP, (unsigned int*)(ws + OFF_BAR));
    k_mega<<<NBLK, NTHR, 0, stream>>>(x, q, Wkv, bkv, Wp1, bp1, Wp2, bp2,
                                      lnw, lnb, (float*)d_out, ws);
}

// Round 2
// 304.074 us; speedup vs baseline: 1.0362x; 1.0362x over previous
//
#include <hip/hip_runtime.h>
#include <math.h>

#define SEQ   8192
#define DIM   2048
#define NH    16
#define DH    128
#define PD    512
#define NBLK  256
#define NTHR  512

static constexpr float LN_EPS = 1e-5f;
static constexpr float SCALE  = 0.08838834764831845f; // 1/sqrt(128)

typedef __bf16 bf16x8 __attribute__((ext_vector_type(8)));
typedef float  f32x4  __attribute__((ext_vector_type(4)));

// ---- workspace layout (floats); all offsets 16B aligned ----
static constexpr size_t OFF_QB   = 0;                    // 16
static constexpr size_t OFF_SMP  = 16;                   // 512 = smp[h][32]
static constexpr size_t OFF_QWB  = 528;                  // 16*2048 bf16 = 16384 floats
static constexpr size_t OFF_PCTX = 16912;                // 256*16*2048 = 8388608
static constexpr size_t OFF_CTX  = OFF_PCTX + 8388608;   // 32768
static constexpr size_t OFF_X1   = OFF_CTX + 32768;      // 2048
static constexpr size_t OFF_H1R  = OFF_X1 + 2048;        // 512
static constexpr size_t OFF_X1F  = OFF_H1R + 512;        // 2048
static constexpr size_t OFF_BAR  = OFF_X1F + 2048;       // 8 uints (barrier counters)

// Device-scope grid barrier. 256 blocks x 512 thr, VGPR<=128 & LDS 15KB =>
// capacity >= 2 blocks/CU on 256 CUs => all 256 blocks co-resident under any
// dispatch order. Counters zeroed by a 32B hipMemsetAsync each call.
// KEY FIX vs prev round: poll with RELAXED loads (no per-poll L2 invalidate);
// exactly ONE acquire fence after the spin exits. The previous ACQUIRE-per-poll
// emitted buffer_inv every ~150 cycles per waiting block, continuously nuking
// the XCD L2 while straggler blocks were still streaming their phase.
__device__ __forceinline__ void gsync(unsigned int* bar) {
    __syncthreads();
    if (threadIdx.x == 0) {
        __threadfence();                       // release: wb dirty L2 (agent)
        __hip_atomic_fetch_add(bar, 1u, __ATOMIC_RELAXED, __HIP_MEMORY_SCOPE_AGENT);
        for (unsigned int it = 0; it < (1u << 21); ++it) {
            unsigned int v = __hip_atomic_load(bar, __ATOMIC_RELAXED,
                                               __HIP_MEMORY_SCOPE_AGENT);
            if (v >= (unsigned int)NBLK) break;
            __builtin_amdgcn_s_sleep(2);
        }
        __builtin_amdgcn_fence(__ATOMIC_ACQUIRE, "agent");  // one inv, not per-poll
    }
    __syncthreads();
}

__global__ __launch_bounds__(NTHR, 2) void k_mega(
    const float* __restrict__ x,   const float* __restrict__ q,
    const float* __restrict__ Wkv, const float* __restrict__ bkv,
    const float* __restrict__ Wp1, const float* __restrict__ bp1,
    const float* __restrict__ Wp2, const float* __restrict__ bp2,
    const float* __restrict__ lnw, const float* __restrict__ lnb,
    float* __restrict__ out, float* __restrict__ ws)
{
    const int b = blockIdx.x, t = threadIdx.x;
    const int w8 = t >> 6, lane = t & 63;

    float*        qb    = ws + OFF_QB;
    float*        smp   = ws + OFF_SMP;
    __bf16*       qWb   = (__bf16*)(ws + OFF_QWB);
    float*        pctx  = ws + OFF_PCTX;
    float*        ctx   = ws + OFF_CTX;
    float*        x1    = ws + OFF_X1;
    float*        h1raw = ws + OFF_H1R;
    float*        x1f   = ws + OFF_X1F;
    unsigned int* bars  = (unsigned int*)(ws + OFF_BAR);

    __shared__ float part[4][128];
    __shared__ float qred[8];
    __shared__ float dpart[2][4][64][4];
    __shared__ float att[32][NH];
    __shared__ float hsum[NH];
    __shared__ float psum[4][128];
    __shared__ float sInv;

    // ================= P0: prep  qWb[h][j]=q_h·W_k[:,j] (bf16), qb[h]=q_h·b_k =================
    {
        const int h = b >> 4, jc = b & 15;
        const int col = t & 127, kh = t >> 7;          // 4 k-groups of 32 d's
        const int j = jc * 128 + col;
        const float* w  = Wkv + (size_t)(h * DH + kh * 32) * DIM + j;
        const float* qh = q + h * DH + kh * 32;
        float acc = 0.f;
#pragma unroll
        for (int d = 0; d < 32; ++d)
            acc += qh[d] * __builtin_nontemporal_load(w + (size_t)d * DIM);
        part[kh][col] = acc;
        if (b == 0) smp[t] = 0.f;                       // smp zero (read after bar1)
        __syncthreads();
        if (kh == 0)
            qWb[h * DIM + j] = (__bf16)(part[0][col] + part[1][col]
                                      + part[2][col] + part[3][col]);
        if (jc == 0) {                                  // block-uniform branch
            float p = (t < DH) ? q[h * DH + t] * bkv[h * DH + t] : 0.f;
            for (int off = 32; off; off >>= 1) p += __shfl_xor(p, off);
            if (lane == 0) qred[w8] = p;
            __syncthreads();
            if (t == 0) {
                float s = 0.f;
#pragma unroll
                for (int i = 0; i < 8; ++i) s += qred[i];
                qb[h] = s;
            }
        }
    }
    gsync(bars + 0);

    // ================= P1: fused logits (MFMA) + unnormalized weighted ctx partials =========
    {
        const int s0 = b * 32;
        const int rg = w8 & 1, kq = w8 >> 1;            // 2 row-groups x 4 K-quarters
        const int r = lane & 15, quad = lane >> 4;
        if (t < NH) hsum[t] = 0.f;

        const float*  xrow = x + (size_t)(s0 + rg * 16 + r) * DIM + quad * 8;
        const __bf16* brow = qWb + r * DIM + quad * 8;  // r doubles as h for B operand
        const int kbase = kq * 512;
        f32x4 acc = {0.f, 0.f, 0.f, 0.f};
#pragma unroll 4
        for (int i = 0; i < 16; ++i) {
            int k = kbase + i * 32;
            float4 xa  = *(const float4*)(xrow + k);
            float4 xb2 = *(const float4*)(xrow + k + 4);
            bf16x8 af;
            af[0] = (__bf16)xa.x;  af[1] = (__bf16)xa.y;
            af[2] = (__bf16)xa.z;  af[3] = (__bf16)xa.w;
            af[4] = (__bf16)xb2.x; af[5] = (__bf16)xb2.y;
            af[6] = (__bf16)xb2.z; af[7] = (__bf16)xb2.w;
            bf16x8 bfv = *(const bf16x8*)(brow + k);
            acc = __builtin_amdgcn_mfma_f32_16x16x32_bf16(af, bfv, acc, 0, 0, 0);
        }
        *(f32x4*)&dpart[rg][kq][lane][0] = acc;
        __syncthreads();

        {   // combine K-quarters -> e = exp((logit+qb)*scale); |logit| <~ 5, no max-sub
            const int h = t & 15, slp = t >> 4;         // slp: 0..31 local row
            const int rg2 = slp >> 4, sli = slp & 15;
            const int quad2 = sli >> 2, reg2 = sli & 3;
            const int lane2 = quad2 * 16 + h;
            float v = dpart[rg2][0][lane2][reg2] + dpart[rg2][1][lane2][reg2]
                    + dpart[rg2][2][lane2][reg2] + dpart[rg2][3][lane2][reg2];
            float e = __expf((v + qb[h]) * SCALE);
            att[slp][h] = e;
            atomicAdd(&hsum[h], e);
        }
        __syncthreads();
        if (t < NH) atomicAdd(&smp[t * 32 + (b & 31)], hsum[t]);

        // phase B: pctx[b][h][j0..j0+4) = sum_rr e[rr][h] * x[s0+rr][j0..j0+4)
        // x rows are L2-hot (just streamed by this block's MFMA phase).
        const int j0 = t * 4;
        f32x4 zero = {0.f, 0.f, 0.f, 0.f};
        f32x4 acc4[NH];
#pragma unroll
        for (int h = 0; h < NH; ++h) acc4[h] = zero;
#pragma unroll 2
        for (int rr = 0; rr < 32; ++rr) {
            f32x4 xv = *(const f32x4*)(x + (size_t)(s0 + rr) * DIM + j0);
            const f32x4* ar = (const f32x4*)att[rr];    // LDS broadcast reads
            f32x4 a0 = ar[0], a1 = ar[1], a2 = ar[2], a3 = ar[3];
            float aa[16];
            *(f32x4*)&aa[0] = a0; *(f32x4*)&aa[4]  = a1;
            *(f32x4*)&aa[8] = a2; *(f32x4*)&aa[12] = a3;
#pragma unroll
            for (int h = 0; h < NH; ++h) acc4[h] += xv * aa[h];
        }
        // NT stores: pctx is write-once, read cross-XCD -> keep L2 clean so the
        // barrier's release writeback is ~free.
#pragma unroll
        for (int h = 0; h < NH; ++h)
            __builtin_nontemporal_store(acc4[h],
                (f32x4*)&pctx[((size_t)(b * NH + h)) * DIM + t * 4]);
    }
    gsync(bars + 1);

    // ================= P2: reduce 256 chunks + softmax normalize =================
    {
        const int h = b >> 4;                           // 128 ctx elems/block, single head
        float v = (t < 32) ? smp[h * 32 + t] : 0.f;
        if (t < 64) {
            for (int off = 16; off; off >>= 1) v += __shfl_xor(v, off);
            if (t == 0) sInv = 1.f / v;
        }
        const int tg = t >> 7, tt = t & 127;
        const size_t idx = (size_t)b * 128 + tt;        // global ctx index
        const int c0 = tg * 64;
        float s = 0.f;
#pragma unroll 8
        for (int c = 0; c < 64; ++c)
            s += __builtin_nontemporal_load(
                     &pctx[(size_t)(c0 + c) * (NH * DIM) + idx]);
        psum[tg][tt] = s;
        __syncthreads();
        if (tg == 0)
            ctx[idx] = (psum[0][tt] + psum[1][tt] + psum[2][tt] + psum[3][tt]) * sInv;
    }
    gsync(bars + 2);

    // ================= P3: x1[row] = ctx[row>>7]·W_v[row] + b_v[row] =================
    {
        const int row = b * 8 + w8;                     // 2048 rows, 1/wave
        const float* wv = Wkv + (size_t)(DIM + row) * DIM;
        const float* cc = ctx + (size_t)(row >> 7) * DIM;
        float acc = 0.f;
#pragma unroll
        for (int i = 0; i < 8; ++i) {
            int j = i * 256 + lane * 4;
            f32x4 a  = __builtin_nontemporal_load((const f32x4*)(wv + j));
            f32x4 c2 = *(const f32x4*)(cc + j);
            acc += a[0]*c2[0] + a[1]*c2[1] + a[2]*c2[2] + a[3]*c2[3];
        }
        for (int off = 32; off; off >>= 1) acc += __shfl_xor(acc, off);
        if (lane == 0) x1[row] = acc + bkv[DIM + row];
    }
    gsync(bars + 3);

    // ================= P4: h1raw[row] = x1·W_p1[row] + b_p1[row] =================
    if (w8 < 2) {                                       // 512 rows, 2/block
        const int row = b * 2 + w8;
        const float* wv = Wp1 + (size_t)row * DIM;
        float acc = 0.f;
#pragma unroll
        for (int i = 0; i < 8; ++i) {
            int j = i * 256 + lane * 4;
            f32x4 a  = __builtin_nontemporal_load((const f32x4*)(wv + j));
            f32x4 c2 = *(const f32x4*)(x1 + j);
            acc += a[0]*c2[0] + a[1]*c2[1] + a[2]*c2[2] + a[3]*c2[3];
        }
        for (int off = 32; off; off >>= 1) acc += __shfl_xor(acc, off);
        if (lane == 0) h1raw[row] = acc + bp1[row];
    }
    gsync(bars + 4);

    // ================= P5: x1f[row] = relu(LN(h1raw))·W_p2[row] + b_p2[row] =================
    {
        const int row = b * 8 + w8;                     // 2048 rows, 1/wave
        const int j = lane * 8;
        f32x4 va  = *(const f32x4*)(h1raw + j);
        f32x4 vb2 = *(const f32x4*)(h1raw + j + 4);
        float s = va[0]+va[1]+va[2]+va[3]+vb2[0]+vb2[1]+vb2[2]+vb2[3];
        for (int off = 32; off; off >>= 1) s += __shfl_xor(s, off);
        float mu = s * (1.0f / PD);
        float dx[8];
        dx[0]=va[0]-mu;  dx[1]=va[1]-mu;  dx[2]=va[2]-mu;  dx[3]=va[3]-mu;
        dx[4]=vb2[0]-mu; dx[5]=vb2[1]-mu; dx[6]=vb2[2]-mu; dx[7]=vb2[3]-mu;
        float s2 = 0.f;
#pragma unroll
        for (int i = 0; i < 8; ++i) s2 += dx[i] * dx[i];
        for (int off = 32; off; off >>= 1) s2 += __shfl_xor(s2, off);
        float rstd = rsqrtf(s2 * (1.0f / PD) + LN_EPS);
        f32x4 lw0 = *(const f32x4*)(lnw + j), lw1 = *(const f32x4*)(lnw + j + 4);
        f32x4 lb0 = *(const f32x4*)(lnb + j), lb1 = *(const f32x4*)(lnb + j + 4);
        float hln[8];
        hln[0]=fmaxf(dx[0]*rstd*lw0[0]+lb0[0],0.f); hln[1]=fmaxf(dx[1]*rstd*lw0[1]+lb0[1],0.f);
        hln[2]=fmaxf(dx[2]*rstd*lw0[2]+lb0[2],0.f); hln[3]=fmaxf(dx[3]*rstd*lw0[3]+lb0[3],0.f);
        hln[4]=fmaxf(dx[4]*rstd*lw1[0]+lb1[0],0.f); hln[5]=fmaxf(dx[5]*rstd*lw1[1]+lb1[1],0.f);
        hln[6]=fmaxf(dx[6]*rstd*lw1[2]+lb1[2],0.f); hln[7]=fmaxf(dx[7]*rstd*lw1[3]+lb1[3],0.f);
        const float* w = Wp2 + (size_t)row * PD + j;
        f32x4 w0 = __builtin_nontemporal_load((const f32x4*)w);
        f32x4 w1 = __builtin_nontemporal_load((const f32x4*)(w + 4));
        float acc = w0[0]*hln[0] + w0[1]*hln[1] + w0[2]*hln[2] + w0[3]*hln[3]
                  + w1[0]*hln[4] + w1[1]*hln[5] + w1[2]*hln[6] + w1[3]*hln[7];
        for (int off = 32; off; off >>= 1) acc += __shfl_xor(acc, off);
        if (lane == 0) x1f[row] = acc + bp2[row];
    }
    gsync(bars + 5);

    // ================= P6: out = x + broadcast(x1f) =================
    {
        const f32x4* x4 = (const f32x4*)x;
        f32x4*       o4 = (f32x4*)out;
        const f32x4  add = ((const f32x4*)x1f)[t];      // (i & 511) == t for all iters
        const size_t base = (size_t)b * NTHR + t;
#pragma unroll 8
        for (int k2 = 0; k2 < 32; ++k2) {
            size_t i = (size_t)k2 * (NBLK * NTHR) + base;
            f32x4 xv = __builtin_nontemporal_load(x4 + i);
            __builtin_nontemporal_store(xv + add, o4 + i);
        }
    }
}

extern "C" void kernel_launch(void* const* d_in, const int* in_sizes, int n_in,
                              void* d_out, int out_size, void* d_ws, size_t ws_size,
                              hipStream_t stream) {
    const float* x    = (const float*)d_in[0];
    const float* q    = (const float*)d_in[1];
    const float* Wkv  = (const float*)d_in[2];
    const float* bkv  = (const float*)d_in[3];
    const float* Wp1  = (const float*)d_in[4];
    const float* bp1  = (const float*)d_in[5];
    const float* Wp2  = (const float*)d_in[6];
    const float* bp2  = (const float*)d_in[7];
    const float* lnw  = (const float*)d_in[8];
    const float* lnb  = (const float*)d_in[9];
    float* ws = (float*)d_ws;

    hipMemsetAsync(ws + OFF_BAR, 0, 8 * sizeof(unsigned int), stream);
    k_mega<<<NBLK, NTHR, 0, stream>>>(x, q, Wkv, bkv, Wp1, bp1, Wp2, bp2,
                                      lnw, lnb, (float*)d_out, ws);
}

// Round 3
// 221.117 us; speedup vs baseline: 1.4250x; 1.3752x over previous
//
#include <hip/hip_runtime.h>
#include <math.h>

#define SEQ   8192
#define DIM   2048
#define NH    16
#define DH    128
#define PD    512

static constexpr float LN_EPS = 1e-5f;
static constexpr float SCALE  = 0.08838834764831845f; // 1/sqrt(128)

typedef __bf16 bf16x8 __attribute__((ext_vector_type(8)));
typedef float  f32x4  __attribute__((ext_vector_type(4)));

// ---- workspace layout (floats); all offsets 16B aligned ----
static constexpr size_t OFF_QB   = 0;                    // 16
static constexpr size_t OFF_SMP  = 16;                   // 512 = smp[h][32]
static constexpr size_t OFF_QWB  = 528;                  // 16*2048 bf16 = 16384 floats
static constexpr size_t OFF_PCTX = 16912;                // 256*16*2048 = 8388608
static constexpr size_t OFF_CTX  = OFF_PCTX + 8388608;   // 32768
static constexpr size_t OFF_X1   = OFF_CTX + 32768;      // 2048
static constexpr size_t OFF_H1R  = OFF_X1 + 2048;        // 512
static constexpr size_t OFF_X1F  = OFF_H1R + 512;        // 2048

// qWb[h][j] = bf16( q_h · W_k[:,j] ), qb[h] = q_h · b_k[h]; zero smp.
// grid 256 = (h 16) x (jc 16); 256 thr: col = t&127, k-half = t>>7
__global__ __launch_bounds__(256) void k_prep(const float* __restrict__ q,
                                              const float* __restrict__ Wkv,
                                              const float* __restrict__ bkv,
                                              __bf16* __restrict__ qWb,
                                              float* __restrict__ qb,
                                              float* __restrict__ smp) {
    int t = threadIdx.x;
    int h = blockIdx.x >> 4, jc = blockIdx.x & 15;
    int col = t & 127, kh = t >> 7;
    int j = jc * 128 + col;
    const float* w  = Wkv + (size_t)(h * DH + kh * 64) * DIM + j;
    const float* qh = q + h * DH + kh * 64;
    float acc = 0.f;
#pragma unroll 16
    for (int d = 0; d < 64; ++d)
        acc += qh[d] * __builtin_nontemporal_load(w + (size_t)d * DIM);
    __shared__ float part[128];
    if (kh) part[col] = acc;
    __syncthreads();
    if (!kh) qWb[h * DIM + j] = (__bf16)(acc + part[col]);
    if (jc == 0 && t < 64) {
        float p = q[h*DH + t] * bkv[h*DH + t] + q[h*DH + 64 + t] * bkv[h*DH + 64 + t];
        for (int off = 32; off; off >>= 1) p += __shfl_down(p, off);
        if (t == 0) qb[h] = p;
    }
    if (blockIdx.x == 0) { smp[t] = 0.f; smp[t + 256] = 0.f; }
}

// Fused: MFMA logits for 32 rows -> e = exp((x·qW+qb)*SCALE) in LDS ->
// UNNORMALIZED weighted ctx partials pctx[b][h][:] = sum_rr e[rr][h]*x[rr][:].
// Reads x exactly once (phase B re-read is L2/L3-hot). Normalization deferred
// to k_ctxred (softmax is linear post-exp). grid 256 x 512 thr (8 waves):
// phase A waves = 2 row-groups x 4 K-quarters. Verified inside round-1/2 mega.
__global__ __launch_bounds__(512) void k_fctx(const float* __restrict__ x,
                                              const __bf16* __restrict__ qWb,
                                              const float* __restrict__ qb,
                                              float* __restrict__ pctx,
                                              float* __restrict__ smp) {
    const int b = blockIdx.x, t = threadIdx.x;
    const int w8 = t >> 6, lane = t & 63;
    const int s0 = b * 32;
    const int rg = w8 & 1, kq = w8 >> 1;
    const int r = lane & 15, quad = lane >> 4;

    __shared__ float dpart[2][4][64][4];
    __shared__ float att[32][NH];
    __shared__ float hsum[NH];
    if (t < NH) hsum[t] = 0.f;

    const float*  xrow = x + (size_t)(s0 + rg * 16 + r) * DIM + quad * 8;
    const __bf16* brow = qWb + r * DIM + quad * 8;  // r doubles as h for B operand
    const int kbase = kq * 512;
    f32x4 acc = {0.f, 0.f, 0.f, 0.f};
#pragma unroll 4
    for (int i = 0; i < 16; ++i) {
        int k = kbase + i * 32;
        float4 xa  = *(const float4*)(xrow + k);
        float4 xb2 = *(const float4*)(xrow + k + 4);
        bf16x8 af;
        af[0] = (__bf16)xa.x;  af[1] = (__bf16)xa.y;
        af[2] = (__bf16)xa.z;  af[3] = (__bf16)xa.w;
        af[4] = (__bf16)xb2.x; af[5] = (__bf16)xb2.y;
        af[6] = (__bf16)xb2.z; af[7] = (__bf16)xb2.w;
        bf16x8 bfv = *(const bf16x8*)(brow + k);
        acc = __builtin_amdgcn_mfma_f32_16x16x32_bf16(af, bfv, acc, 0, 0, 0);
    }
    *(f32x4*)&dpart[rg][kq][lane][0] = acc;
    __syncthreads();

    {   // combine K-quarters -> e; |logit*SCALE| <~ 5 so no max-subtraction
        const int h = t & 15, slp = t >> 4;
        const int rg2 = slp >> 4, sli = slp & 15;
        const int quad2 = sli >> 2, reg2 = sli & 3;
        const int lane2 = quad2 * 16 + h;
        float v = dpart[rg2][0][lane2][reg2] + dpart[rg2][1][lane2][reg2]
                + dpart[rg2][2][lane2][reg2] + dpart[rg2][3][lane2][reg2];
        float e = __expf((v + qb[h]) * SCALE);
        att[slp][h] = e;
        atomicAdd(&hsum[h], e);
    }
    __syncthreads();
    if (t < NH) atomicAdd(&smp[t * 32 + (b & 31)], hsum[t]);

    // phase B: weighted sum; x rows L2-hot from phase A.
    const int j0 = t * 4;
    f32x4 zero = {0.f, 0.f, 0.f, 0.f};
    f32x4 acc4[NH];
#pragma unroll
    for (int h = 0; h < NH; ++h) acc4[h] = zero;
#pragma unroll 2
    for (int rr = 0; rr < 32; ++rr) {
        f32x4 xv = *(const f32x4*)(x + (size_t)(s0 + rr) * DIM + j0);
        const f32x4* ar = (const f32x4*)att[rr];        // LDS broadcast reads
        f32x4 a0 = ar[0], a1 = ar[1], a2 = ar[2], a3 = ar[3];
        float aa[16];
        *(f32x4*)&aa[0] = a0; *(f32x4*)&aa[4]  = a1;
        *(f32x4*)&aa[8] = a2; *(f32x4*)&aa[12] = a3;
#pragma unroll
        for (int h = 0; h < NH; ++h) acc4[h] += xv * aa[h];
    }
    // NT stores: pctx is write-once/read-once -> don't pollute L2 (keep x hot).
#pragma unroll
    for (int h = 0; h < NH; ++h)
        __builtin_nontemporal_store(acc4[h],
            (f32x4*)&pctx[((size_t)(b * NH + h)) * DIM + j0]);
}

// ctx[idx] = (sum_{c<256} pctx[c][idx]) / S[head(idx)]
// grid 128 x 256 thr: idx = b*256+t, single head per block (b>>3).
__global__ __launch_bounds__(256) void k_ctxred(const float* __restrict__ pctx,
                                                const float* __restrict__ smp,
                                                float* __restrict__ ctx) {
    const int b = blockIdx.x, t = threadIdx.x;
    const int h = b >> 3;                              // 8 blocks per head
    __shared__ float sInv;
    if (t < 32) {
        float v = smp[h * 32 + t];
        for (int off = 16; off; off >>= 1) v += __shfl_xor(v, off);
        if (t == 0) sInv = 1.0f / v;
    }
    __syncthreads();
    const size_t idx = (size_t)b * 256 + t;
    float s = 0.f;
#pragma unroll 8
    for (int c = 0; c < 256; ++c)
        s += __builtin_nontemporal_load(&pctx[(size_t)c * (NH * DIM) + idx]);
    ctx[idx] = s * sInv;
}

// x1[row] = ctx[row>>7]·W_v[row] + b_kv[DIM+row]; one wave/row, 4 rows/block
__global__ __launch_bounds__(256) void k_x1(const float* __restrict__ Wkv,
                                            const float* __restrict__ bkv,
                                            const float* __restrict__ ctx,
                                            float* __restrict__ x1) {
    int row = blockIdx.x * 4 + (threadIdx.x >> 6);
    int lane = threadIdx.x & 63;
    const float* w = Wkv + (size_t)(DIM + row) * DIM;
    const float* c = ctx + (row >> 7) * DIM;
    float acc = 0.f;
#pragma unroll
    for (int k = 0; k < 8; ++k) {
        int j = k * 256 + lane * 4;
        f32x4 wv = __builtin_nontemporal_load((const f32x4*)&w[j]);
        f32x4 cv = *(const f32x4*)&c[j];
        acc += wv[0]*cv[0] + wv[1]*cv[1] + wv[2]*cv[2] + wv[3]*cv[3];
    }
    for (int off = 32; off; off >>= 1) acc += __shfl_xor(acc, off);
    if (lane == 0) x1[row] = acc + bkv[DIM + row];
}

// h1raw[row] = x1·W_p1[row] + b_p1[row]
__global__ __launch_bounds__(256) void k_h1(const float* __restrict__ Wp1,
                                            const float* __restrict__ bp1,
                                            const float* __restrict__ x1,
                                            float* __restrict__ h1raw) {
    int row = blockIdx.x * 4 + (threadIdx.x >> 6);
    int lane = threadIdx.x & 63;
    const float* w = Wp1 + (size_t)row * DIM;
    float acc = 0.f;
#pragma unroll
    for (int k = 0; k < 8; ++k) {
        int j = k * 256 + lane * 4;
        f32x4 wv = __builtin_nontemporal_load((const f32x4*)&w[j]);
        f32x4 cv = *(const f32x4*)&x1[j];
        acc += wv[0]*cv[0] + wv[1]*cv[1] + wv[2]*cv[2] + wv[3]*cv[3];
    }
    for (int off = 32; off; off >>= 1) acc += __shfl_xor(acc, off);
    if (lane == 0) h1raw[row] = acc + bp1[row];
}

// Fused LN+relu+proj2: x1f[row] = relu(LN(h1raw))·W_p2[row] + b_p2[row]
__global__ __launch_bounds__(256) void k_x1f(const float* __restrict__ Wp2,
                                             const float* __restrict__ bp2,
                                             const float* __restrict__ h1raw,
                                             const float* __restrict__ lnw,
                                             const float* __restrict__ lnb,
                                             float* __restrict__ x1f) {
    int row = blockIdx.x * 4 + (threadIdx.x >> 6);
    int lane = threadIdx.x & 63;
    int j = lane * 8;
    float4 va = *(const float4*)&h1raw[j];
    float4 vb = *(const float4*)&h1raw[j + 4];
    float s = va.x + va.y + va.z + va.w + vb.x + vb.y + vb.z + vb.w;
    for (int off = 32; off; off >>= 1) s += __shfl_xor(s, off);
    float mu = s * (1.0f / PD);
    float dx[8];
    dx[0]=va.x-mu; dx[1]=va.y-mu; dx[2]=va.z-mu; dx[3]=va.w-mu;
    dx[4]=vb.x-mu; dx[5]=vb.y-mu; dx[6]=vb.z-mu; dx[7]=vb.w-mu;
    float s2 = 0.f;
#pragma unroll
    for (int i = 0; i < 8; ++i) s2 += dx[i] * dx[i];
    for (int off = 32; off; off >>= 1) s2 += __shfl_xor(s2, off);
    float rstd = rsqrtf(s2 * (1.0f / PD) + LN_EPS);
    float4 lw0 = *(const float4*)&lnw[j], lw1 = *(const float4*)&lnw[j + 4];
    float4 lb0 = *(const float4*)&lnb[j], lb1 = *(const float4*)&lnb[j + 4];
    float hln[8];
    hln[0]=fmaxf(dx[0]*rstd*lw0.x+lb0.x,0.f); hln[1]=fmaxf(dx[1]*rstd*lw0.y+lb0.y,0.f);
    hln[2]=fmaxf(dx[2]*rstd*lw0.z+lb0.z,0.f); hln[3]=fmaxf(dx[3]*rstd*lw0.w+lb0.w,0.f);
    hln[4]=fmaxf(dx[4]*rstd*lw1.x+lb1.x,0.f); hln[5]=fmaxf(dx[5]*rstd*lw1.y+lb1.y,0.f);
    hln[6]=fmaxf(dx[6]*rstd*lw1.z+lb1.z,0.f); hln[7]=fmaxf(dx[7]*rstd*lw1.w+lb1.w,0.f);
    const float* w = Wp2 + (size_t)row * PD + j;
    f32x4 w0 = __builtin_nontemporal_load((const f32x4*)w);
    f32x4 w1 = __builtin_nontemporal_load((const f32x4*)(w + 4));
    float acc = w0[0]*hln[0] + w0[1]*hln[1] + w0[2]*hln[2] + w0[3]*hln[3]
              + w1[0]*hln[4] + w1[1]*hln[5] + w1[2]*hln[6] + w1[3]*hln[7];
    for (int off = 32; off; off >>= 1) acc += __shfl_xor(acc, off);
    if (lane == 0) x1f[row] = acc + bp2[row];
}

// out[s][j] = x[s][j] + x1f[j]; 2 float4/thread, NT stores (write-once)
__global__ __launch_bounds__(256) void k_out(const float* __restrict__ x,
                                             const float* __restrict__ x1f,
                                             float* __restrict__ out) {
    size_t i = (size_t)blockIdx.x * 512 + threadIdx.x;
    f32x4 xv = ((const f32x4*)x)[i];
    f32x4 a  = ((const f32x4*)x1f)[(int)(i & 511)];
    __builtin_nontemporal_store(xv + a, (f32x4*)out + i);
    size_t i2 = i + 256;
    f32x4 xv2 = ((const f32x4*)x)[i2];
    f32x4 a2  = ((const f32x4*)x1f)[(int)(i2 & 511)];
    __builtin_nontemporal_store(xv2 + a2, (f32x4*)out + i2);
}

extern "C" void kernel_launch(void* const* d_in, const int* in_sizes, int n_in,
                              void* d_out, int out_size, void* d_ws, size_t ws_size,
                              hipStream_t stream) {
    const float* x    = (const float*)d_in[0];
    const float* q    = (const float*)d_in[1];
    const float* Wkv  = (const float*)d_in[2];
    const float* bkv  = (const float*)d_in[3];
    const float* Wp1  = (const float*)d_in[4];
    const float* bp1  = (const float*)d_in[5];
    const float* Wp2  = (const float*)d_in[6];
    const float* bp2  = (const float*)d_in[7];
    const float* lnw  = (const float*)d_in[8];
    const float* lnb  = (const float*)d_in[9];
    float* out = (float*)d_out;
    float* ws  = (float*)d_ws;

    float*  qb    = ws + OFF_QB;
    float*  smp   = ws + OFF_SMP;
    __bf16* qWb   = (__bf16*)(ws + OFF_QWB);
    float*  pctx  = ws + OFF_PCTX;
    float*  ctx   = ws + OFF_CTX;
    float*  x1    = ws + OFF_X1;
    float*  h1raw = ws + OFF_H1R;
    float*  x1f   = ws + OFF_X1F;

    k_prep  <<<256, 256, 0, stream>>>(q, Wkv, bkv, qWb, qb, smp);
    k_fctx  <<<256, 512, 0, stream>>>(x, qWb, qb, pctx, smp);
    k_ctxred<<<128, 256, 0, stream>>>(pctx, smp, ctx);
    k_x1    <<<512, 256, 0, stream>>>(Wkv, bkv, ctx, x1);
    k_h1    <<<128, 256, 0, stream>>>(Wp1, bp1, x1, h1raw);
    k_x1f   <<<512, 256, 0, stream>>>(Wp2, bp2, h1raw, lnw, lnb, x1f);
    k_out   <<<8192, 256, 0, stream>>>(x, x1f, out);
}

// Round 4
// 212.290 us; speedup vs baseline: 1.4843x; 1.0416x over previous
//
#include <hip/hip_runtime.h>
#include <math.h>

#define SEQ   8192
#define DIM   2048
#define NH    16
#define DH    128
#define PD    512

static constexpr float LN_EPS = 1e-5f;
static constexpr float SCALE  = 0.08838834764831845f; // 1/sqrt(128)

typedef __bf16 bf16x8 __attribute__((ext_vector_type(8)));
typedef float  f32x4  __attribute__((ext_vector_type(4)));
typedef float  f32x2  __attribute__((ext_vector_type(2)));

// ---- workspace layout (floats); all offsets 16B aligned ----
static constexpr size_t OFF_QB   = 0;                    // 16
static constexpr size_t OFF_SMP  = 16;                   // 512 = smp[h][32]
static constexpr size_t OFF_QWB  = 528;                  // 16*2048 bf16 = 16384 floats
static constexpr size_t OFF_PCTX = 16912;                // 256*16*2048 = 8388608
static constexpr size_t OFF_CTX  = OFF_PCTX + 8388608;   // 32768
static constexpr size_t OFF_X1   = OFF_CTX + 32768;      // 2048
static constexpr size_t OFF_H1R  = OFF_X1 + 2048;        // 512
static constexpr size_t OFF_X1F  = OFF_H1R + 512;        // 2048

// qWb[h][j] = bf16( q_h · W_k[:,j] ), qb[h] = q_h · b_k[h]; zero smp.
// grid 256 = (h 16) x (jc 16); 256 thr: col = t&127, k-half = t>>7
__global__ __launch_bounds__(256) void k_prep(const float* __restrict__ q,
                                              const float* __restrict__ Wkv,
                                              const float* __restrict__ bkv,
                                              __bf16* __restrict__ qWb,
                                              float* __restrict__ qb,
                                              float* __restrict__ smp) {
    int t = threadIdx.x;
    int h = blockIdx.x >> 4, jc = blockIdx.x & 15;
    int col = t & 127, kh = t >> 7;
    int j = jc * 128 + col;
    const float* w  = Wkv + (size_t)(h * DH + kh * 64) * DIM + j;
    const float* qh = q + h * DH + kh * 64;
    float acc = 0.f;
#pragma unroll 16
    for (int d = 0; d < 64; ++d)
        acc += qh[d] * __builtin_nontemporal_load(w + (size_t)d * DIM);
    __shared__ float part[128];
    if (kh) part[col] = acc;
    __syncthreads();
    if (!kh) qWb[h * DIM + j] = (__bf16)(acc + part[col]);
    if (jc == 0 && t < 64) {
        float p = q[h*DH + t] * bkv[h*DH + t] + q[h*DH + 64 + t] * bkv[h*DH + 64 + t];
        for (int off = 32; off; off >>= 1) p += __shfl_down(p, off);
        if (t == 0) qb[h] = p;
    }
    if (blockIdx.x == 0) { smp[t] = 0.f; smp[t + 256] = 0.f; }
}

// Fused: MFMA logits for 32 rows -> e = exp((x·qW+qb)*SCALE) in LDS ->
// UNNORMALIZED weighted ctx partials pctx[b][h][:] = sum_rr e[rr][h]*x[rr][:].
// ROUND-4 CHANGE: 1024 thr/block (16 waves/CU = 50% occupancy; was 8 waves =
// 2.35 TB/s latency-bound). Phase A: 2 row-groups x 8 K-eighths, 8 MFMA/wave.
// Phase B: f32x2/thread (64 lanes x 8B = 512B/instr, fully coalesced).
__global__ __launch_bounds__(1024) void k_fctx(const float* __restrict__ x,
                                               const __bf16* __restrict__ qWb,
                                               const float* __restrict__ qb,
                                               float* __restrict__ pctx,
                                               float* __restrict__ smp) {
    const int b = blockIdx.x, t = threadIdx.x;
    const int w16 = t >> 6, lane = t & 63;
    const int s0 = b * 32;
    const int rg = w16 & 1, kq = w16 >> 1;          // 2 row-groups x 8 K-eighths
    const int r = lane & 15, quad = lane >> 4;

    __shared__ float dpart[2][8][64][4];            // 16 KB
    __shared__ float att[32][NH];
    __shared__ float hsum[NH];
    if (t < NH) hsum[t] = 0.f;

    const float*  xrow = x + (size_t)(s0 + rg * 16 + r) * DIM + quad * 8;
    const __bf16* brow = qWb + r * DIM + quad * 8;  // r doubles as h for B operand
    const int kbase = kq * 256;
    f32x4 acc = {0.f, 0.f, 0.f, 0.f};
#pragma unroll
    for (int i = 0; i < 8; ++i) {
        int k = kbase + i * 32;
        float4 xa  = *(const float4*)(xrow + k);
        float4 xb2 = *(const float4*)(xrow + k + 4);
        bf16x8 af;
        af[0] = (__bf16)xa.x;  af[1] = (__bf16)xa.y;
        af[2] = (__bf16)xa.z;  af[3] = (__bf16)xa.w;
        af[4] = (__bf16)xb2.x; af[5] = (__bf16)xb2.y;
        af[6] = (__bf16)xb2.z; af[7] = (__bf16)xb2.w;
        bf16x8 bfv = *(const bf16x8*)(brow + k);
        acc = __builtin_amdgcn_mfma_f32_16x16x32_bf16(af, bfv, acc, 0, 0, 0);
    }
    *(f32x4*)&dpart[rg][kq][lane][0] = acc;
    __syncthreads();

    if (t < 512) {  // combine 8 K-eighths -> e; |logit*SCALE| <~ 5, no max-sub
        const int h = t & 15, slp = t >> 4;
        const int rg2 = slp >> 4, sli = slp & 15;
        const int quad2 = sli >> 2, reg2 = sli & 3;
        const int lane2 = quad2 * 16 + h;
        float v = 0.f;
#pragma unroll
        for (int kk = 0; kk < 8; ++kk) v += dpart[rg2][kk][lane2][reg2];
        float e = __expf((v + qb[h]) * SCALE);
        att[slp][h] = e;
        atomicAdd(&hsum[h], e);
    }
    __syncthreads();
    if (t < NH) atomicAdd(&smp[t * 32 + (b & 31)], hsum[t]);

    // phase B: weighted sum; x rows L2/L3-hot from phase A.
    const int j0 = t * 2;
    f32x2 acc2[NH];
#pragma unroll
    for (int h = 0; h < NH; ++h) acc2[h] = (f32x2){0.f, 0.f};
#pragma unroll 2
    for (int rr = 0; rr < 32; ++rr) {
        f32x2 xv = *(const f32x2*)(x + (size_t)(s0 + rr) * DIM + j0);
        const f32x4* ar = (const f32x4*)att[rr];    // LDS broadcast reads
        f32x4 a0 = ar[0], a1 = ar[1], a2 = ar[2], a3 = ar[3];
        float aa[16];
        *(f32x4*)&aa[0] = a0; *(f32x4*)&aa[4]  = a1;
        *(f32x4*)&aa[8] = a2; *(f32x4*)&aa[12] = a3;
#pragma unroll
        for (int h = 0; h < NH; ++h) {
            acc2[h][0] += xv[0] * aa[h];
            acc2[h][1] += xv[1] * aa[h];
        }
    }
    // NT stores: pctx is write-once/read-once -> don't pollute L2 (keep x hot).
#pragma unroll
    for (int h = 0; h < NH; ++h)
        __builtin_nontemporal_store(acc2[h],
            (f32x2*)&pctx[((size_t)(b * NH + h)) * DIM + j0]);
}

// ctx[idx] = (sum_{c<256} pctx[c][idx]) / S[head(idx)]
// ROUND-4 CHANGE: grid 512 (was 128: half the CUs idle). Each block owns 64
// outputs; 4-way chunk-split (t>>6) + LDS combine.
__global__ __launch_bounds__(256) void k_ctxred(const float* __restrict__ pctx,
                                                const float* __restrict__ smp,
                                                float* __restrict__ ctx) {
    const int b = blockIdx.x, t = threadIdx.x;
    const int h = b >> 5;                          // 32 blocks per head
    const int col = t & 63, ch = t >> 6;           // ch = chunk quarter
    __shared__ float sInv;
    __shared__ float psum[4][64];
    const size_t idx = (size_t)b * 64 + col;
    const int c0 = ch * 64;
    float s = 0.f;
#pragma unroll 16
    for (int c = 0; c < 64; ++c)
        s += __builtin_nontemporal_load(&pctx[(size_t)(c0 + c) * (NH * DIM) + idx]);
    psum[ch][col] = s;
    if (t < 32) {
        float v = smp[h * 32 + t];
        for (int off = 16; off; off >>= 1) v += __shfl_xor(v, off);
        if (t == 0) sInv = 1.0f / v;
    }
    __syncthreads();
    if (ch == 0)
        ctx[idx] = (psum[0][col] + psum[1][col] + psum[2][col] + psum[3][col]) * sInv;
}

// x1[row] = ctx[row>>7]·W_v[row] + b_kv[DIM+row]; one wave/row, 4 rows/block
__global__ __launch_bounds__(256) void k_x1(const float* __restrict__ Wkv,
                                            const float* __restrict__ bkv,
                                            const float* __restrict__ ctx,
                                            float* __restrict__ x1) {
    int row = blockIdx.x * 4 + (threadIdx.x >> 6);
    int lane = threadIdx.x & 63;
    const float* w = Wkv + (size_t)(DIM + row) * DIM;
    const float* c = ctx + (row >> 7) * DIM;
    float acc = 0.f;
#pragma unroll
    for (int k = 0; k < 8; ++k) {
        int j = k * 256 + lane * 4;
        f32x4 wv = __builtin_nontemporal_load((const f32x4*)&w[j]);
        f32x4 cv = *(const f32x4*)&c[j];
        acc += wv[0]*cv[0] + wv[1]*cv[1] + wv[2]*cv[2] + wv[3]*cv[3];
    }
    for (int off = 32; off; off >>= 1) acc += __shfl_xor(acc, off);
    if (lane == 0) x1[row] = acc + bkv[DIM + row];
}

// h1raw[row] = x1·W_p1[row] + b_p1[row]
__global__ __launch_bounds__(256) void k_h1(const float* __restrict__ Wp1,
                                            const float* __restrict__ bp1,
                                            const float* __restrict__ x1,
                                            float* __restrict__ h1raw) {
    int row = blockIdx.x * 4 + (threadIdx.x >> 6);
    int lane = threadIdx.x & 63;
    const float* w = Wp1 + (size_t)row * DIM;
    float acc = 0.f;
#pragma unroll
    for (int k = 0; k < 8; ++k) {
        int j = k * 256 + lane * 4;
        f32x4 wv = __builtin_nontemporal_load((const f32x4*)&w[j]);
        f32x4 cv = *(const f32x4*)&x1[j];
        acc += wv[0]*cv[0] + wv[1]*cv[1] + wv[2]*cv[2] + wv[3]*cv[3];
    }
    for (int off = 32; off; off >>= 1) acc += __shfl_xor(acc, off);
    if (lane == 0) h1raw[row] = acc + bp1[row];
}

// Fused LN+relu+proj2: x1f[row] = relu(LN(h1raw))·W_p2[row] + b_p2[row]
__global__ __launch_bounds__(256) void k_x1f(const float* __restrict__ Wp2,
                                             const float* __restrict__ bp2,
                                             const float* __restrict__ h1raw,
                                             const float* __restrict__ lnw,
                                             const float* __restrict__ lnb,
                                             float* __restrict__ x1f) {
    int row = blockIdx.x * 4 + (threadIdx.x >> 6);
    int lane = threadIdx.x & 63;
    int j = lane * 8;
    float4 va = *(const float4*)&h1raw[j];
    float4 vb = *(const float4*)&h1raw[j + 4];
    float s = va.x + va.y + va.z + va.w + vb.x + vb.y + vb.z + vb.w;
    for (int off = 32; off; off >>= 1) s += __shfl_xor(s, off);
    float mu = s * (1.0f / PD);
    float dx[8];
    dx[0]=va.x-mu; dx[1]=va.y-mu; dx[2]=va.z-mu; dx[3]=va.w-mu;
    dx[4]=vb.x-mu; dx[5]=vb.y-mu; dx[6]=vb.z-mu; dx[7]=vb.w-mu;
    float s2 = 0.f;
#pragma unroll
    for (int i = 0; i < 8; ++i) s2 += dx[i] * dx[i];
    for (int off = 32; off; off >>= 1) s2 += __shfl_xor(s2, off);
    float rstd = rsqrtf(s2 * (1.0f / PD) + LN_EPS);
    float4 lw0 = *(const float4*)&lnw[j], lw1 = *(const float4*)&lnw[j + 4];
    float4 lb0 = *(const float4*)&lnb[j], lb1 = *(const float4*)&lnb[j + 4];
    float hln[8];
    hln[0]=fmaxf(dx[0]*rstd*lw0.x+lb0.x,0.f); hln[1]=fmaxf(dx[1]*rstd*lw0.y+lb0.y,0.f);
    hln[2]=fmaxf(dx[2]*rstd*lw0.z+lb0.z,0.f); hln[3]=fmaxf(dx[3]*rstd*lw0.w+lb0.w,0.f);
    hln[4]=fmaxf(dx[4]*rstd*lw1.x+lb1.x,0.f); hln[5]=fmaxf(dx[5]*rstd*lw1.y+lb1.y,0.f);
    hln[6]=fmaxf(dx[6]*rstd*lw1.z+lb1.z,0.f); hln[7]=fmaxf(dx[7]*rstd*lw1.w+lb1.w,0.f);
    const float* w = Wp2 + (size_t)row * PD + j;
    f32x4 w0 = __builtin_nontemporal_load((const f32x4*)w);
    f32x4 w1 = __builtin_nontemporal_load((const f32x4*)(w + 4));
    float acc = w0[0]*hln[0] + w0[1]*hln[1] + w0[2]*hln[2] + w0[3]*hln[3]
              + w1[0]*hln[4] + w1[1]*hln[5] + w1[2]*hln[6] + w1[3]*hln[7];
    for (int off = 32; off; off >>= 1) acc += __shfl_xor(acc, off);
    if (lane == 0) x1f[row] = acc + bp2[row];
}

// out[s][j] = x[s][j] + x1f[j]; 2 float4/thread, NT stores (write-once)
__global__ __launch_bounds__(256) void k_out(const float* __restrict__ x,
                                             const float* __restrict__ x1f,
                                             float* __restrict__ out) {
    size_t i = (size_t)blockIdx.x * 512 + threadIdx.x;
    f32x4 xv = ((const f32x4*)x)[i];
    f32x4 a  = ((const f32x4*)x1f)[(int)(i & 511)];
    __builtin_nontemporal_store(xv + a, (f32x4*)out + i);
    size_t i2 = i + 256;
    f32x4 xv2 = ((const f32x4*)x)[i2];
    f32x4 a2  = ((const f32x4*)x1f)[(int)(i2 & 511)];
    __builtin_nontemporal_store(xv2 + a2, (f32x4*)out + i2);
}

extern "C" void kernel_launch(void* const* d_in, const int* in_sizes, int n_in,
                              void* d_out, int out_size, void* d_ws, size_t ws_size,
                              hipStream_t stream) {
    const float* x    = (const float*)d_in[0];
    const float* q    = (const float*)d_in[1];
    const float* Wkv  = (const float*)d_in[2];
    const float* bkv  = (const float*)d_in[3];
    const float* Wp1  = (const float*)d_in[4];
    const float* bp1  = (const float*)d_in[5];
    const float* Wp2  = (const float*)d_in[6];
    const float* bp2  = (const float*)d_in[7];
    const float* lnw  = (const float*)d_in[8];
    const float* lnb  = (const float*)d_in[9];
    float* out = (float*)d_out;
    float* ws  = (float*)d_ws;

    float*  qb    = ws + OFF_QB;
    float*  smp   = ws + OFF_SMP;
    __bf16* qWb   = (__bf16*)(ws + OFF_QWB);
    float*  pctx  = ws + OFF_PCTX;
    float*  ctx   = ws + OFF_CTX;
    float*  x1    = ws + OFF_X1;
    float*  h1raw = ws + OFF_H1R;
    float*  x1f   = ws + OFF_X1F;

    k_prep  <<<256, 256,  0, stream>>>(q, Wkv, bkv, qWb, qb, smp);
    k_fctx  <<<256, 1024, 0, stream>>>(x, qWb, qb, pctx, smp);
    k_ctxred<<<512, 256,  0, stream>>>(pctx, smp, ctx);
    k_x1    <<<512, 256,  0, stream>>>(Wkv, bkv, ctx, x1);
    k_h1    <<<128, 256,  0, stream>>>(Wp1, bp1, x1, h1raw);
    k_x1f   <<<512, 256,  0, stream>>>(Wp2, bp2, h1raw, lnw, lnb, x1f);
    k_out   <<<8192, 256, 0, stream>>>(x, x1f, out);
}

// Round 5
// 209.869 us; speedup vs baseline: 1.5014x; 1.0115x over previous
//
#include <hip/hip_runtime.h>
#include <math.h>

#define SEQ   8192
#define DIM   2048
#define NH    16
#define DH    128
#define PD    512

static constexpr float LN_EPS = 1e-5f;
static constexpr float SCALE  = 0.08838834764831845f; // 1/sqrt(128)

typedef __bf16 bf16x8 __attribute__((ext_vector_type(8)));
typedef float  f32x4  __attribute__((ext_vector_type(4)));

// ---- workspace layout (floats); all offsets 16B aligned ----
static constexpr size_t OFF_QB   = 0;                    // 16
static constexpr size_t OFF_SMP  = 16;                   // 512 = smp[h][32]
static constexpr size_t OFF_QWB  = 528;                  // 16*2048 bf16 = 16384 floats
static constexpr size_t OFF_PCTX = 16912;                // 256*16*2048 = 8388608
static constexpr size_t OFF_CTX  = OFF_PCTX + 8388608;   // 32768
static constexpr size_t OFF_X1   = OFF_CTX + 32768;      // 2048
static constexpr size_t OFF_H1R  = OFF_X1 + 2048;        // 512
static constexpr size_t OFF_X1F  = OFF_H1R + 512;        // 2048

// qWb[h][j] = bf16( q_h · W_k[:,j] ), qb[h] = q_h · b_k[h]; zero smp.
// grid 256 = (h 16) x (jc 16); 256 thr: col = t&127, k-half = t>>7
__global__ __launch_bounds__(256) void k_prep(const float* __restrict__ q,
                                              const float* __restrict__ Wkv,
                                              const float* __restrict__ bkv,
                                              __bf16* __restrict__ qWb,
                                              float* __restrict__ qb,
                                              float* __restrict__ smp) {
    int t = threadIdx.x;
    int h = blockIdx.x >> 4, jc = blockIdx.x & 15;
    int col = t & 127, kh = t >> 7;
    int j = jc * 128 + col;
    const float* w  = Wkv + (size_t)(h * DH + kh * 64) * DIM + j;
    const float* qh = q + h * DH + kh * 64;
    float acc = 0.f;
#pragma unroll 16
    for (int d = 0; d < 64; ++d)
        acc += qh[d] * __builtin_nontemporal_load(w + (size_t)d * DIM);
    __shared__ float part[128];
    if (kh) part[col] = acc;
    __syncthreads();
    if (!kh) qWb[h * DIM + j] = (__bf16)(acc + part[col]);
    if (jc == 0 && t < 64) {
        float p = q[h*DH + t] * bkv[h*DH + t] + q[h*DH + 64 + t] * bkv[h*DH + 64 + t];
        for (int off = 32; off; off >>= 1) p += __shfl_down(p, off);
        if (t == 0) qb[h] = p;
    }
    if (blockIdx.x == 0) { smp[t] = 0.f; smp[t + 256] = 0.f; }
}

// Fused: MFMA logits for 32 rows -> e in LDS -> unnormalized weighted ctx
// partials pctx[b][h][:] = sum_rr e[rr][h]*x[rr][:].
// ROUND-5 CHANGE: round-4 showed occupancy is NOT the limiter (17.9%->34.5%
// gave 0% speedup; VGPR_Count=36 => compiler kept ~2 load-pairs in flight).
// Force per-wave load ILP: preload ALL 16 x load-pairs (128 VGPRs, 16KB
// outstanding/wave) + qWb fragments 8-deep before the MFMA chain.
// 512 thr (VGPR cap 256, no spill risk): 2 row-groups x 4 K-quarters.
__global__ __launch_bounds__(512) void k_fctx(const float* __restrict__ x,
                                              const __bf16* __restrict__ qWb,
                                              const float* __restrict__ qb,
                                              float* __restrict__ pctx,
                                              float* __restrict__ smp) {
    const int b = blockIdx.x, t = threadIdx.x;
    const int w8 = t >> 6, lane = t & 63;
    const int s0 = b * 32;
    const int rg = w8 & 1, kq = w8 >> 1;
    const int r = lane & 15, quad = lane >> 4;

    __shared__ float dpart[2][4][64][4];
    __shared__ float att[32][NH];
    __shared__ float hsum[NH];
    if (t < NH) hsum[t] = 0.f;

    const float*  xrow = x + (size_t)(s0 + rg * 16 + r) * DIM + quad * 8;
    const __bf16* brow = qWb + r * DIM + quad * 8;  // r doubles as h for B operand
    const int kbase = kq * 512;

    // ---- phase A: deep-hoisted load stream + MFMA chain ----
    float4 XA[16], XB[16];
#pragma unroll
    for (int i = 0; i < 16; ++i) {
        XA[i] = *(const float4*)(xrow + kbase + i * 32);
        XB[i] = *(const float4*)(xrow + kbase + i * 32 + 4);
    }
    bf16x8 WV[8];
#pragma unroll
    for (int i = 0; i < 8; ++i)
        WV[i] = *(const bf16x8*)(brow + kbase + i * 32);

    f32x4 acc = {0.f, 0.f, 0.f, 0.f};
#pragma unroll
    for (int i = 0; i < 8; ++i) {
        bf16x8 af;
        af[0] = (__bf16)XA[i].x; af[1] = (__bf16)XA[i].y;
        af[2] = (__bf16)XA[i].z; af[3] = (__bf16)XA[i].w;
        af[4] = (__bf16)XB[i].x; af[5] = (__bf16)XB[i].y;
        af[6] = (__bf16)XB[i].z; af[7] = (__bf16)XB[i].w;
        acc = __builtin_amdgcn_mfma_f32_16x16x32_bf16(af, WV[i], acc, 0, 0, 0);
    }
#pragma unroll
    for (int i = 0; i < 8; ++i)
        WV[i] = *(const bf16x8*)(brow + kbase + (8 + i) * 32);
#pragma unroll
    for (int i = 0; i < 8; ++i) {
        bf16x8 af;
        af[0] = (__bf16)XA[8+i].x; af[1] = (__bf16)XA[8+i].y;
        af[2] = (__bf16)XA[8+i].z; af[3] = (__bf16)XA[8+i].w;
        af[4] = (__bf16)XB[8+i].x; af[5] = (__bf16)XB[8+i].y;
        af[6] = (__bf16)XB[8+i].z; af[7] = (__bf16)XB[8+i].w;
        acc = __builtin_amdgcn_mfma_f32_16x16x32_bf16(af, WV[i], acc, 0, 0, 0);
    }
    *(f32x4*)&dpart[rg][kq][lane][0] = acc;
    __syncthreads();

    {   // combine K-quarters -> e; |logit*SCALE| <~ 5 so no max-subtraction
        const int h = t & 15, slp = t >> 4;
        const int rg2 = slp >> 4, sli = slp & 15;
        const int quad2 = sli >> 2, reg2 = sli & 3;
        const int lane2 = quad2 * 16 + h;
        float v = dpart[rg2][0][lane2][reg2] + dpart[rg2][1][lane2][reg2]
                + dpart[rg2][2][lane2][reg2] + dpart[rg2][3][lane2][reg2];
        float e = __expf((v + qb[h]) * SCALE);
        att[slp][h] = e;
        atomicAdd(&hsum[h], e);
    }
    __syncthreads();
    if (t < NH) atomicAdd(&smp[t * 32 + (b & 31)], hsum[t]);

    // ---- phase B: weighted sum; x rows L2-hot from phase A ----
    const int j0 = t * 4;
    f32x4 zero = {0.f, 0.f, 0.f, 0.f};
    f32x4 acc4[NH];
#pragma unroll
    for (int h = 0; h < NH; ++h) acc4[h] = zero;
#pragma unroll 4
    for (int rr = 0; rr < 32; ++rr) {
        f32x4 xv = *(const f32x4*)(x + (size_t)(s0 + rr) * DIM + j0);
        const f32x4* ar = (const f32x4*)att[rr];    // LDS broadcast reads
        f32x4 a0 = ar[0], a1 = ar[1], a2 = ar[2], a3 = ar[3];
        float aa[16];
        *(f32x4*)&aa[0] = a0; *(f32x4*)&aa[4]  = a1;
        *(f32x4*)&aa[8] = a2; *(f32x4*)&aa[12] = a3;
#pragma unroll
        for (int h = 0; h < NH; ++h) acc4[h] += xv * aa[h];
    }
    // NT stores: pctx is write-once/read-once -> don't pollute L2 (keep x hot).
#pragma unroll
    for (int h = 0; h < NH; ++h)
        __builtin_nontemporal_store(acc4[h],
            (f32x4*)&pctx[((size_t)(b * NH + h)) * DIM + j0]);
}

// ctx[idx] = (sum_{c<256} pctx[c][idx]) / S[head(idx)]
// grid 512; each block owns 64 outputs; 4-way chunk-split + LDS combine.
__global__ __launch_bounds__(256) void k_ctxred(const float* __restrict__ pctx,
                                                const float* __restrict__ smp,
                                                float* __restrict__ ctx) {
    const int b = blockIdx.x, t = threadIdx.x;
    const int h = b >> 5;                          // 32 blocks per head
    const int col = t & 63, ch = t >> 6;           // ch = chunk quarter
    __shared__ float sInv;
    __shared__ float psum[4][64];
    const size_t idx = (size_t)b * 64 + col;
    const int c0 = ch * 64;
    float s = 0.f;
#pragma unroll 16
    for (int c = 0; c < 64; ++c)
        s += __builtin_nontemporal_load(&pctx[(size_t)(c0 + c) * (NH * DIM) + idx]);
    psum[ch][col] = s;
    if (t < 32) {
        float v = smp[h * 32 + t];
        for (int off = 16; off; off >>= 1) v += __shfl_xor(v, off);
        if (t == 0) sInv = 1.0f / v;
    }
    __syncthreads();
    if (ch == 0)
        ctx[idx] = (psum[0][col] + psum[1][col] + psum[2][col] + psum[3][col]) * sInv;
}

// x1[row] = ctx[row>>7]·W_v[row] + b_kv[DIM+row]; one wave/row, 4 rows/block
__global__ __launch_bounds__(256) void k_x1(const float* __restrict__ Wkv,
                                            const float* __restrict__ bkv,
                                            const float* __restrict__ ctx,
                                            float* __restrict__ x1) {
    int row = blockIdx.x * 4 + (threadIdx.x >> 6);
    int lane = threadIdx.x & 63;
    const float* w = Wkv + (size_t)(DIM + row) * DIM;
    const float* c = ctx + (row >> 7) * DIM;
    float acc = 0.f;
#pragma unroll
    for (int k = 0; k < 8; ++k) {
        int j = k * 256 + lane * 4;
        f32x4 wv = __builtin_nontemporal_load((const f32x4*)&w[j]);
        f32x4 cv = *(const f32x4*)&c[j];
        acc += wv[0]*cv[0] + wv[1]*cv[1] + wv[2]*cv[2] + wv[3]*cv[3];
    }
    for (int off = 32; off; off >>= 1) acc += __shfl_xor(acc, off);
    if (lane == 0) x1[row] = acc + bkv[DIM + row];
}

// h1raw[row] = x1·W_p1[row] + b_p1[row]
__global__ __launch_bounds__(256) void k_h1(const float* __restrict__ Wp1,
                                            const float* __restrict__ bp1,
                                            const float* __restrict__ x1,
                                            float* __restrict__ h1raw) {
    int row = blockIdx.x * 4 + (threadIdx.x >> 6);
    int lane = threadIdx.x & 63;
    const float* w = Wp1 + (size_t)row * DIM;
    float acc = 0.f;
#pragma unroll
    for (int k = 0; k < 8; ++k) {
        int j = k * 256 + lane * 4;
        f32x4 wv = __builtin_nontemporal_load((const f32x4*)&w[j]);
        f32x4 cv = *(const f32x4*)&x1[j];
        acc += wv[0]*cv[0] + wv[1]*cv[1] + wv[2]*cv[2] + wv[3]*cv[3];
    }
    for (int off = 32; off; off >>= 1) acc += __shfl_xor(acc, off);
    if (lane == 0) h1raw[row] = acc + bp1[row];
}

// Fused LN+relu+proj2: x1f[row] = relu(LN(h1raw))·W_p2[row] + b_p2[row]
__global__ __launch_bounds__(256) void k_x1f(const float* __restrict__ Wp2,
                                             const float* __restrict__ bp2,
                                             const float* __restrict__ h1raw,
                                             const float* __restrict__ lnw,
                                             const float* __restrict__ lnb,
                                             float* __restrict__ x1f) {
    int row = blockIdx.x * 4 + (threadIdx.x >> 6);
    int lane = threadIdx.x & 63;
    int j = lane * 8;
    float4 va = *(const float4*)&h1raw[j];
    float4 vb = *(const float4*)&h1raw[j + 4];
    float s = va.x + va.y + va.z + va.w + vb.x + vb.y + vb.z + vb.w;
    for (int off = 32; off; off >>= 1) s += __shfl_xor(s, off);
    float mu = s * (1.0f / PD);
    float dx[8];
    dx[0]=va.x-mu; dx[1]=va.y-mu; dx[2]=va.z-mu; dx[3]=va.w-mu;
    dx[4]=vb.x-mu; dx[5]=vb.y-mu; dx[6]=vb.z-mu; dx[7]=vb.w-mu;
    float s2 = 0.f;
#pragma unroll
    for (int i = 0; i < 8; ++i) s2 += dx[i] * dx[i];
    for (int off = 32; off; off >>= 1) s2 += __shfl_xor(s2, off);
    float rstd = rsqrtf(s2 * (1.0f / PD) + LN_EPS);
    float4 lw0 = *(const float4*)&lnw[j], lw1 = *(const float4*)&lnw[j + 4];
    float4 lb0 = *(const float4*)&lnb[j], lb1 = *(const float4*)&lnb[j + 4];
    float hln[8];
    hln[0]=fmaxf(dx[0]*rstd*lw0.x+lb0.x,0.f); hln[1]=fmaxf(dx[1]*rstd*lw0.y+lb0.y,0.f);
    hln[2]=fmaxf(dx[2]*rstd*lw0.z+lb0.z,0.f); hln[3]=fmaxf(dx[3]*rstd*lw0.w+lb0.w,0.f);
    hln[4]=fmaxf(dx[4]*rstd*lw1.x+lb1.x,0.f); hln[5]=fmaxf(dx[5]*rstd*lw1.y+lb1.y,0.f);
    hln[6]=fmaxf(dx[6]*rstd*lw1.z+lb1.z,0.f); hln[7]=fmaxf(dx[7]*rstd*lw1.w+lb1.w,0.f);
    const float* w = Wp2 + (size_t)row * PD + j;
    f32x4 w0 = __builtin_nontemporal_load((const f32x4*)w);
    f32x4 w1 = __builtin_nontemporal_load((const f32x4*)(w + 4));
    float acc = w0[0]*hln[0] + w0[1]*hln[1] + w0[2]*hln[2] + w0[3]*hln[3]
              + w1[0]*hln[4] + w1[1]*hln[5] + w1[2]*hln[6] + w1[3]*hln[7];
    for (int off = 32; off; off >>= 1) acc += __shfl_xor(acc, off);
    if (lane == 0) x1f[row] = acc + bp2[row];
}

// out[s][j] = x[s][j] + x1f[j]; 2 float4/thread, NT stores (write-once)
__global__ __launch_bounds__(256) void k_out(const float* __restrict__ x,
                                             const float* __restrict__ x1f,
                                             float* __restrict__ out) {
    size_t i = (size_t)blockIdx.x * 512 + threadIdx.x;
    f32x4 xv = ((const f32x4*)x)[i];
    f32x4 a  = ((const f32x4*)x1f)[(int)(i & 511)];
    __builtin_nontemporal_store(xv + a, (f32x4*)out + i);
    size_t i2 = i + 256;
    f32x4 xv2 = ((const f32x4*)x)[i2];
    f32x4 a2  = ((const f32x4*)x1f)[(int)(i2 & 511)];
    __builtin_nontemporal_store(xv2 + a2, (f32x4*)out + i2);
}

extern "C" void kernel_launch(void* const* d_in, const int* in_sizes, int n_in,
                              void* d_out, int out_size, void* d_ws, size_t ws_size,
                              hipStream_t stream) {
    const float* x    = (const float*)d_in[0];
    const float* q    = (const float*)d_in[1];
    const float* Wkv  = (const float*)d_in[2];
    const float* bkv  = (const float*)d_in[3];
    const float* Wp1  = (const float*)d_in[4];
    const float* bp1  = (const float*)d_in[5];
    const float* Wp2  = (const float*)d_in[6];
    const float* bp2  = (const float*)d_in[7];
    const float* lnw  = (const float*)d_in[8];
    const float* lnb  = (const float*)d_in[9];
    float* out = (float*)d_out;
    float* ws  = (float*)d_ws;

    float*  qb    = ws + OFF_QB;
    float*  smp   = ws + OFF_SMP;
    __bf16* qWb   = (__bf16*)(ws + OFF_QWB);
    float*  pctx  = ws + OFF_PCTX;
    float*  ctx   = ws + OFF_CTX;
    float*  x1    = ws + OFF_X1;
    float*  h1raw = ws + OFF_H1R;
    float*  x1f   = ws + OFF_X1F;

    k_prep  <<<256, 256, 0, stream>>>(q, Wkv, bkv, qWb, qb, smp);
    k_fctx  <<<256, 512, 0, stream>>>(x, qWb, qb, pctx, smp);
    k_ctxred<<<512, 256, 0, stream>>>(pctx, smp, ctx);
    k_x1    <<<512, 256, 0, stream>>>(Wkv, bkv, ctx, x1);
    k_h1    <<<128, 256, 0, stream>>>(Wp1, bp1, x1, h1raw);
    k_x1f   <<<512, 256, 0, stream>>>(Wp2, bp2, h1raw, lnw, lnb, x1f);
    k_out   <<<8192, 256, 0, stream>>>(x, x1f, out);
}

// Round 6
// 208.946 us; speedup vs baseline: 1.5080x; 1.0044x over previous
//
#include <hip/hip_runtime.h>
#include <math.h>

#define SEQ   8192
#define DIM   2048
#define NH    16
#define DH    128
#define PD    512

static constexpr float LN_EPS = 1e-5f;
static constexpr float SCALE  = 0.08838834764831845f; // 1/sqrt(128)

typedef __bf16 bf16x8 __attribute__((ext_vector_type(8)));
typedef float  f32x4  __attribute__((ext_vector_type(4)));

// ---- workspace layout (floats); all offsets 16B aligned ----
static constexpr size_t OFF_QB   = 0;                    // 16
static constexpr size_t OFF_SMP  = 16;                   // 512 = smp[h][32]
static constexpr size_t OFF_QWB  = 528;                  // 16*2048 bf16 = 16384 floats
static constexpr size_t OFF_PCTX = 16912;                // 256*16*2048 = 8388608
static constexpr size_t OFF_CTX  = OFF_PCTX + 8388608;   // 32768
static constexpr size_t OFF_X1   = OFF_CTX + 32768;      // 2048
static constexpr size_t OFF_H1R  = OFF_X1 + 2048;        // 512
static constexpr size_t OFF_X1F  = OFF_H1R + 512;        // 2048

// qWb[h][j] = bf16( q_h · W_k[:,j] ), qb[h] = q_h · b_k[h]; zero smp.
// grid 256 = (h 16) x (jc 16); 256 thr: col = t&127, k-half = t>>7
__global__ __launch_bounds__(256) void k_prep(const float* __restrict__ q,
                                              const float* __restrict__ Wkv,
                                              const float* __restrict__ bkv,
                                              __bf16* __restrict__ qWb,
                                              float* __restrict__ qb,
                                              float* __restrict__ smp) {
    int t = threadIdx.x;
    int h = blockIdx.x >> 4, jc = blockIdx.x & 15;
    int col = t & 127, kh = t >> 7;
    int j = jc * 128 + col;
    const float* w  = Wkv + (size_t)(h * DH + kh * 64) * DIM + j;
    const float* qh = q + h * DH + kh * 64;
    float acc = 0.f;
#pragma unroll 16
    for (int d = 0; d < 64; ++d)
        acc += qh[d] * __builtin_nontemporal_load(w + (size_t)d * DIM);
    __shared__ float part[128];
    if (kh) part[col] = acc;
    __syncthreads();
    if (!kh) qWb[h * DIM + j] = (__bf16)(acc + part[col]);
    if (jc == 0 && t < 64) {
        float p = q[h*DH + t] * bkv[h*DH + t] + q[h*DH + 64 + t] * bkv[h*DH + 64 + t];
        for (int off = 32; off; off >>= 1) p += __shfl_down(p, off);
        if (t == 0) qb[h] = p;
    }
    if (blockIdx.x == 0) { smp[t] = 0.f; smp[t + 256] = 0.f; }
}

// Fused: MFMA logits for 32 rows -> e in LDS -> unnormalized weighted ctx
// partials pctx[b][h][:] = sum_rr e[rr][h]*x[rr][:].
// ROUND-6 CHANGE: round-5's reg-array "preload" was SUNK by the scheduler
// (VGPR_Count=52, not ~180 -> loads went back into the loop; perf identical).
// Pin it with __builtin_amdgcn_sched_barrier(0): all 48 loads (16 qWb frags +
// 32 x float4) issue BEFORE the fence; MFMA chain after. ~24KB outstanding
// per wave, ~190KB/CU >> ~9KB needed to cover 900cy HBM latency.
__global__ __launch_bounds__(512) void k_fctx(const float* __restrict__ x,
                                              const __bf16* __restrict__ qWb,
                                              const float* __restrict__ qb,
                                              float* __restrict__ pctx,
                                              float* __restrict__ smp) {
    const int b = blockIdx.x, t = threadIdx.x;
    const int w8 = t >> 6, lane = t & 63;
    const int s0 = b * 32;
    const int rg = w8 & 1, kq = w8 >> 1;
    const int r = lane & 15, quad = lane >> 4;

    __shared__ float dpart[2][4][64][4];
    __shared__ float att[32][NH];
    __shared__ float hsum[NH];
    if (t < NH) hsum[t] = 0.f;

    const float*  xrow = x + (size_t)(s0 + rg * 16 + r) * DIM + quad * 8;
    const __bf16* brow = qWb + r * DIM + quad * 8;  // r doubles as h for B operand
    const int kbase = kq * 512;

    // ---- phase A: issue ALL loads, then fence, then MFMA chain drains ----
    bf16x8 WV[16];
#pragma unroll
    for (int i = 0; i < 16; ++i)
        WV[i] = *(const bf16x8*)(brow + kbase + i * 32);   // L2-hot (64KB shared)
    float4 XA[16], XB[16];
#pragma unroll
    for (int i = 0; i < 16; ++i) {
        XA[i] = *(const float4*)(xrow + kbase + i * 32);
        XB[i] = *(const float4*)(xrow + kbase + i * 32 + 4);
    }
    __builtin_amdgcn_sched_barrier(0);   // nothing crosses: loads stay hoisted

    f32x4 acc = {0.f, 0.f, 0.f, 0.f};
#pragma unroll
    for (int i = 0; i < 16; ++i) {
        bf16x8 af;
        af[0] = (__bf16)XA[i].x; af[1] = (__bf16)XA[i].y;
        af[2] = (__bf16)XA[i].z; af[3] = (__bf16)XA[i].w;
        af[4] = (__bf16)XB[i].x; af[5] = (__bf16)XB[i].y;
        af[6] = (__bf16)XB[i].z; af[7] = (__bf16)XB[i].w;
        acc = __builtin_amdgcn_mfma_f32_16x16x32_bf16(af, WV[i], acc, 0, 0, 0);
    }
    *(f32x4*)&dpart[rg][kq][lane][0] = acc;
    __syncthreads();

    {   // combine K-quarters -> e; |logit*SCALE| <~ 5 so no max-subtraction
        const int h = t & 15, slp = t >> 4;
        const int rg2 = slp >> 4, sli = slp & 15;
        const int quad2 = sli >> 2, reg2 = sli & 3;
        const int lane2 = quad2 * 16 + h;
        float v = dpart[rg2][0][lane2][reg2] + dpart[rg2][1][lane2][reg2]
                + dpart[rg2][2][lane2][reg2] + dpart[rg2][3][lane2][reg2];
        float e = __expf((v + qb[h]) * SCALE);
        att[slp][h] = e;
        atomicAdd(&hsum[h], e);
    }
    __syncthreads();
    if (t < NH) atomicAdd(&smp[t * 32 + (b & 31)], hsum[t]);

    // ---- phase B: weighted sum; x rows L2/L3-hot from phase A ----
    const int j0 = t * 4;
    f32x4 zero = {0.f, 0.f, 0.f, 0.f};
    f32x4 acc4[NH];
#pragma unroll
    for (int h = 0; h < NH; ++h) acc4[h] = zero;
#pragma unroll 4
    for (int rr = 0; rr < 32; ++rr) {
        f32x4 xv = *(const f32x4*)(x + (size_t)(s0 + rr) * DIM + j0);
        const f32x4* ar = (const f32x4*)att[rr];    // LDS broadcast reads
        f32x4 a0 = ar[0], a1 = ar[1], a2 = ar[2], a3 = ar[3];
        float aa[16];
        *(f32x4*)&aa[0] = a0; *(f32x4*)&aa[4]  = a1;
        *(f32x4*)&aa[8] = a2; *(f32x4*)&aa[12] = a3;
#pragma unroll
        for (int h = 0; h < NH; ++h) acc4[h] += xv * aa[h];
    }
    // NT stores: pctx is write-once/read-once -> don't pollute L2 (keep x hot).
#pragma unroll
    for (int h = 0; h < NH; ++h)
        __builtin_nontemporal_store(acc4[h],
            (f32x4*)&pctx[((size_t)(b * NH + h)) * DIM + j0]);
}

// ctx[idx] = (sum_{c<256} pctx[c][idx]) / S[head(idx)]
// grid 512; each block owns 64 outputs; 4-way chunk-split + LDS combine.
__global__ __launch_bounds__(256) void k_ctxred(const float* __restrict__ pctx,
                                                const float* __restrict__ smp,
                                                float* __restrict__ ctx) {
    const int b = blockIdx.x, t = threadIdx.x;
    const int h = b >> 5;                          // 32 blocks per head
    const int col = t & 63, ch = t >> 6;           // ch = chunk quarter
    __shared__ float sInv;
    __shared__ float psum[4][64];
    const size_t idx = (size_t)b * 64 + col;
    const int c0 = ch * 64;
    float s = 0.f;
#pragma unroll 16
    for (int c = 0; c < 64; ++c)
        s += __builtin_nontemporal_load(&pctx[(size_t)(c0 + c) * (NH * DIM) + idx]);
    psum[ch][col] = s;
    if (t < 32) {
        float v = smp[h * 32 + t];
        for (int off = 16; off; off >>= 1) v += __shfl_xor(v, off);
        if (t == 0) sInv = 1.0f / v;
    }
    __syncthreads();
    if (ch == 0)
        ctx[idx] = (psum[0][col] + psum[1][col] + psum[2][col] + psum[3][col]) * sInv;
}

// x1[row] = ctx[row>>7]·W_v[row] + b_kv[DIM+row]; one wave/row, 4 rows/block
__global__ __launch_bounds__(256) void k_x1(const float* __restrict__ Wkv,
                                            const float* __restrict__ bkv,
                                            const float* __restrict__ ctx,
                                            float* __restrict__ x1) {
    int row = blockIdx.x * 4 + (threadIdx.x >> 6);
    int lane = threadIdx.x & 63;
    const float* w = Wkv + (size_t)(DIM + row) * DIM;
    const float* c = ctx + (row >> 7) * DIM;
    float acc = 0.f;
#pragma unroll
    for (int k = 0; k < 8; ++k) {
        int j = k * 256 + lane * 4;
        f32x4 wv = __builtin_nontemporal_load((const f32x4*)&w[j]);
        f32x4 cv = *(const f32x4*)&c[j];
        acc += wv[0]*cv[0] + wv[1]*cv[1] + wv[2]*cv[2] + wv[3]*cv[3];
    }
    for (int off = 32; off; off >>= 1) acc += __shfl_xor(acc, off);
    if (lane == 0) x1[row] = acc + bkv[DIM + row];
}

// h1raw[row] = x1·W_p1[row] + b_p1[row]
__global__ __launch_bounds__(256) void k_h1(const float* __restrict__ Wp1,
                                            const float* __restrict__ bp1,
                                            const float* __restrict__ x1,
                                            float* __restrict__ h1raw) {
    int row = blockIdx.x * 4 + (threadIdx.x >> 6);
    int lane = threadIdx.x & 63;
    const float* w = Wp1 + (size_t)row * DIM;
    float acc = 0.f;
#pragma unroll
    for (int k = 0; k < 8; ++k) {
        int j = k * 256 + lane * 4;
        f32x4 wv = __builtin_nontemporal_load((const f32x4*)&w[j]);
        f32x4 cv = *(const f32x4*)&x1[j];
        acc += wv[0]*cv[0] + wv[1]*cv[1] + wv[2]*cv[2] + wv[3]*cv[3];
    }
    for (int off = 32; off; off >>= 1) acc += __shfl_xor(acc, off);
    if (lane == 0) h1raw[row] = acc + bp1[row];
}

// Fused LN+relu+proj2: x1f[row] = relu(LN(h1raw))·W_p2[row] + b_p2[row]
__global__ __launch_bounds__(256) void k_x1f(const float* __restrict__ Wp2,
                                             const float* __restrict__ bp2,
                                             const float* __restrict__ h1raw,
                                             const float* __restrict__ lnw,
                                             const float* __restrict__ lnb,
                                             float* __restrict__ x1f) {
    int row = blockIdx.x * 4 + (threadIdx.x >> 6);
    int lane = threadIdx.x & 63;
    int j = lane * 8;
    float4 va = *(const float4*)&h1raw[j];
    float4 vb = *(const float4*)&h1raw[j + 4];
    float s = va.x + va.y + va.z + va.w + vb.x + vb.y + vb.z + vb.w;
    for (int off = 32; off; off >>= 1) s += __shfl_xor(s, off);
    float mu = s * (1.0f / PD);
    float dx[8];
    dx[0]=va.x-mu; dx[1]=va.y-mu; dx[2]=va.z-mu; dx[3]=va.w-mu;
    dx[4]=vb.x-mu; dx[5]=vb.y-mu; dx[6]=vb.z-mu; dx[7]=vb.w-mu;
    float s2 = 0.f;
#pragma unroll
    for (int i = 0; i < 8; ++i) s2 += dx[i] * dx[i];
    for (int off = 32; off; off >>= 1) s2 += __shfl_xor(s2, off);
    float rstd = rsqrtf(s2 * (1.0f / PD) + LN_EPS);
    float4 lw0 = *(const float4*)&lnw[j], lw1 = *(const float4*)&lnw[j + 4];
    float4 lb0 = *(const float4*)&lnb[j], lb1 = *(const float4*)&lnb[j + 4];
    float hln[8];
    hln[0]=fmaxf(dx[0]*rstd*lw0.x+lb0.x,0.f); hln[1]=fmaxf(dx[1]*rstd*lw0.y+lb0.y,0.f);
    hln[2]=fmaxf(dx[2]*rstd*lw0.z+lb0.z,0.f); hln[3]=fmaxf(dx[3]*rstd*lw0.w+lb0.w,0.f);
    hln[4]=fmaxf(dx[4]*rstd*lw1.x+lb1.x,0.f); hln[5]=fmaxf(dx[5]*rstd*lw1.y+lb1.y,0.f);
    hln[6]=fmaxf(dx[6]*rstd*lw1.z+lb1.z,0.f); hln[7]=fmaxf(dx[7]*rstd*lw1.w+lb1.w,0.f);
    const float* w = Wp2 + (size_t)row * PD + j;
    f32x4 w0 = __builtin_nontemporal_load((const f32x4*)w);
    f32x4 w1 = __builtin_nontemporal_load((const f32x4*)(w + 4));
    float acc = w0[0]*hln[0] + w0[1]*hln[1] + w0[2]*hln[2] + w0[3]*hln[3]
              + w1[0]*hln[4] + w1[1]*hln[5] + w1[2]*hln[6] + w1[3]*hln[7];
    for (int off = 32; off; off >>= 1) acc += __shfl_xor(acc, off);
    if (lane == 0) x1f[row] = acc + bp2[row];
}

// out[s][j] = x[s][j] + x1f[j]; 2 float4/thread, NT stores (write-once)
__global__ __launch_bounds__(256) void k_out(const float* __restrict__ x,
                                             const float* __restrict__ x1f,
                                             float* __restrict__ out) {
    size_t i = (size_t)blockIdx.x * 512 + threadIdx.x;
    f32x4 xv = ((const f32x4*)x)[i];
    f32x4 a  = ((const f32x4*)x1f)[(int)(i & 511)];
    __builtin_nontemporal_store(xv + a, (f32x4*)out + i);
    size_t i2 = i + 256;
    f32x4 xv2 = ((const f32x4*)x)[i2];
    f32x4 a2  = ((const f32x4*)x1f)[(int)(i2 & 511)];
    __builtin_nontemporal_store(xv2 + a2, (f32x4*)out + i2);
}

extern "C" void kernel_launch(void* const* d_in, const int* in_sizes, int n_in,
                              void* d_out, int out_size, void* d_ws, size_t ws_size,
                              hipStream_t stream) {
    const float* x    = (const float*)d_in[0];
    const float* q    = (const float*)d_in[1];
    const float* Wkv  = (const float*)d_in[2];
    const float* bkv  = (const float*)d_in[3];
    const float* Wp1  = (const float*)d_in[4];
    const float* bp1  = (const float*)d_in[5];
    const float* Wp2  = (const float*)d_in[6];
    const float* bp2  = (const float*)d_in[7];
    const float* lnw  = (const float*)d_in[8];
    const float* lnb  = (const float*)d_in[9];
    float* out = (float*)d_out;
    float* ws  = (float*)d_ws;

    float*  qb    = ws + OFF_QB;
    float*  smp   = ws + OFF_SMP;
    __bf16* qWb   = (__bf16*)(ws + OFF_QWB);
    float*  pctx  = ws + OFF_PCTX;
    float*  ctx   = ws + OFF_CTX;
    float*  x1    = ws + OFF_X1;
    float*  h1raw = ws + OFF_H1R;
    float*  x1f   = ws + OFF_X1F;

    k_prep  <<<256, 256, 0, stream>>>(q, Wkv, bkv, qWb, qb, smp);
    k_fctx  <<<256, 512, 0, stream>>>(x, qWb, qb, pctx, smp);
    k_ctxred<<<512, 256, 0, stream>>>(pctx, smp, ctx);
    k_x1    <<<512, 256, 0, stream>>>(Wkv, bkv, ctx, x1);
    k_h1    <<<128, 256, 0, stream>>>(Wp1, bp1, x1, h1raw);
    k_x1f   <<<512, 256, 0, stream>>>(Wp2, bp2, h1raw, lnw, lnb, x1f);
    k_out   <<<8192, 256, 0, stream>>>(x, x1f, out);
}

// Round 8
// 206.747 us; speedup vs baseline: 1.5241x; 1.0106x over previous
//
#include <hip/hip_runtime.h>
#include <math.h>

#define SEQ   8192
#define DIM   2048
#define NH    16
#define DH    128
#define PD    512

static constexpr float LN_EPS = 1e-5f;
static constexpr float SCALE  = 0.08838834764831845f; // 1/sqrt(128)

typedef __bf16 bf16x8 __attribute__((ext_vector_type(8)));
typedef float  f32x4  __attribute__((ext_vector_type(4)));

// ---- workspace layout (floats); all offsets 16B aligned ----
static constexpr size_t OFF_QB   = 0;                    // 16
static constexpr size_t OFF_SMP  = 16;                   // 512 = smp[h][32]
static constexpr size_t OFF_QWB  = 528;                  // 16*2048 bf16 = 16384 floats
static constexpr size_t OFF_PCTX = 16912;                // 256*16*2048 = 8388608
static constexpr size_t OFF_CTX  = OFF_PCTX + 8388608;   // 32768
static constexpr size_t OFF_X1   = OFF_CTX + 32768;      // 2048
static constexpr size_t OFF_H1R  = OFF_X1 + 2048;        // 512
static constexpr size_t OFF_X1F  = OFF_H1R + 512;        // 2048

// async 16B global->LDS DMA (no VGPR round-trip; depth limited by vmcnt queue,
// not registers -- the fix for rounds 4-6's ~2-outstanding-load ceiling).
// lds ptr is per-lane base+lane*16 (HW takes lane0 as wave base).
__device__ __forceinline__ void gload_lds16(const float* g, float* l) {
    __builtin_amdgcn_global_load_lds(
        (const __attribute__((address_space(1))) uint32_t*)g,
        (__attribute__((address_space(3))) uint32_t*)l,
        16, 0, 0);
}

// qWb[h][j] = bf16( q_h · W_k[:,j] ), qb[h] = q_h · b_k[h]; zero smp.
// grid 256 = (h 16) x (jc 16); 256 thr: col = t&127, k-half = t>>7
__global__ __launch_bounds__(256) void k_prep(const float* __restrict__ q,
                                              const float* __restrict__ Wkv,
                                              const float* __restrict__ bkv,
                                              __bf16* __restrict__ qWb,
                                              float* __restrict__ qb,
                                              float* __restrict__ smp) {
    int t = threadIdx.x;
    int h = blockIdx.x >> 4, jc = blockIdx.x & 15;
    int col = t & 127, kh = t >> 7;
    int j = jc * 128 + col;
    const float* w  = Wkv + (size_t)(h * DH + kh * 64) * DIM + j;
    const float* qh = q + h * DH + kh * 64;
    float acc = 0.f;
#pragma unroll 16
    for (int d = 0; d < 64; ++d)
        acc += qh[d] * __builtin_nontemporal_load(w + (size_t)d * DIM);
    __shared__ float part[128];
    if (kh) part[col] = acc;
    __syncthreads();
    if (!kh) qWb[h * DIM + j] = (__bf16)(acc + part[col]);
    if (jc == 0 && t < 64) {
        float p = q[h*DH + t] * bkv[h*DH + t] + q[h*DH + 64 + t] * bkv[h*DH + 64 + t];
        for (int off = 32; off; off >>= 1) p += __shfl_down(p, off);
        if (t == 0) qb[h] = p;
    }
    if (blockIdx.x == 0) { smp[t] = 0.f; smp[t + 256] = 0.f; }
}

// Fused logits+ctx: LDS-DMA staged.
// Per block: 32 rows in 2 half-tiles of 16. Each half:
//   1) stage 16 rows fp32 -> LDS via global_load_lds (128 async 1KB DMAs)
//   2) vmcnt(0)+barrier
//   3) phase A: MFMA logits, A-frags from LDS ds_read_b128, B=qWb (L2-hot)
//   4) combine K-eighths -> e = exp((logit+qb)*SCALE) -> att, hsum
//   5) phase B: pctx partial accumulation reading x from LDS (conflict-free)
// Rows padded +4 floats so phase-A strided reads stay near the b128 floor.
#define ROWF 2052   // 2048 + 4 pad floats; 16 rows = 131,328 B LDS
__global__ __launch_bounds__(512) void k_fctx(const float* __restrict__ x,
                                              const __bf16* __restrict__ qWb,
                                              const float* __restrict__ qb,
                                              float* __restrict__ pctx,
                                              float* __restrict__ smp) {
    const int b = blockIdx.x, t = threadIdx.x;
    const int w8 = t >> 6, lane = t & 63;
    const int s0 = b * 32;
    const int r = lane & 15, quad = lane >> 4;

    __shared__ float ldsx[16 * ROWF];       // 128.25 KB staged x half-tile
    __shared__ float dpart[8][64][4];       // 8 KB  K-eighth partials
    __shared__ float att[16][NH];           // 1 KB
    __shared__ float hsum[NH];
    if (t < NH) hsum[t] = 0.f;

    const int kbase = w8 * 256;             // this wave's K-eighth
    const int j0 = t * 4;                   // phase-B column
    f32x4 acc4[NH];
#pragma unroll
    for (int h = 0; h < NH; ++h) acc4[h] = (f32x4){0.f, 0.f, 0.f, 0.f};

    for (int h2 = 0; h2 < 2; ++h2) {
        if (h2) __syncthreads();            // phase B of prev half done with LDS
        // ---- 1) async stage 16 rows; wave w8 stages bytes [w8*1KB, +1KB) of each row
        {
            const float* gsrc = x + (size_t)(s0 + h2 * 16) * DIM + kbase + lane * 4;
            float*       ldst = ldsx + kbase + lane * 4;
#pragma unroll
            for (int i = 0; i < 16; ++i)
                gload_lds16(gsrc + (size_t)i * DIM, ldst + i * ROWF);
        }
        asm volatile("s_waitcnt vmcnt(0)" ::: "memory");
        __syncthreads();

        // ---- 3) phase A: MFMA over this wave's K-eighth (8 x K=32)
        {
            const __bf16* brow = qWb + r * DIM + kbase + quad * 8;
            const float*  lrow = ldsx + r * ROWF + kbase + quad * 8;
            f32x4 acc = {0.f, 0.f, 0.f, 0.f};
#pragma unroll
            for (int i = 0; i < 8; ++i) {
                f32x4 xa = *(const f32x4*)(lrow + i * 32);
                f32x4 xb = *(const f32x4*)(lrow + i * 32 + 4);
                bf16x8 af;
                af[0] = (__bf16)xa[0]; af[1] = (__bf16)xa[1];
                af[2] = (__bf16)xa[2]; af[3] = (__bf16)xa[3];
                af[4] = (__bf16)xb[0]; af[5] = (__bf16)xb[1];
                af[6] = (__bf16)xb[2]; af[7] = (__bf16)xb[3];
                bf16x8 bv = *(const bf16x8*)(brow + i * 32);
                acc = __builtin_amdgcn_mfma_f32_16x16x32_bf16(af, bv, acc, 0, 0, 0);
            }
            *(f32x4*)&dpart[w8][lane][0] = acc;
        }
        __syncthreads();

        // ---- 4) combine 8 K-eighths -> e; |logit*SCALE| <~ 5, no max-sub
        if (t < 256) {
            const int h = t & 15, sl = t >> 4;
            const int quad2 = sl >> 2, reg2 = sl & 3;
            const int lane2 = quad2 * 16 + h;
            float v = 0.f;
#pragma unroll
            for (int kk = 0; kk < 8; ++kk) v += dpart[kk][lane2][reg2];
            float e = __expf((v + qb[h]) * SCALE);
            att[sl][h] = e;
            atomicAdd(&hsum[h], e);
        }
        __syncthreads();

        // ---- 5) phase B: acc4[h] += e[rr][h] * x[rr][j0..j0+4) from LDS
#pragma unroll 4
        for (int rr = 0; rr < 16; ++rr) {
            f32x4 xv = *(const f32x4*)(ldsx + rr * ROWF + j0);
            const f32x4* ar = (const f32x4*)att[rr];   // LDS broadcast
            f32x4 a0 = ar[0], a1 = ar[1], a2 = ar[2], a3 = ar[3];
            float aa[16];
            *(f32x4*)&aa[0] = a0; *(f32x4*)&aa[4]  = a1;
            *(f32x4*)&aa[8] = a2; *(f32x4*)&aa[12] = a3;
#pragma unroll
            for (int h = 0; h < NH; ++h) acc4[h] += xv * aa[h];
        }
    }

    if (t < NH) atomicAdd(&smp[t * 32 + (b & 31)], hsum[t]);
    // NT stores: pctx write-once/read-once; keep L2 clean.
#pragma unroll
    for (int h = 0; h < NH; ++h)
        __builtin_nontemporal_store(acc4[h],
            (f32x4*)&pctx[((size_t)(b * NH + h)) * DIM + j0]);
}
#undef ROWF

// ctx[idx] = (sum_{c<256} pctx[c][idx]) / S[head(idx)]
// grid 512; each block owns 64 outputs; 4-way chunk-split + LDS combine.
__global__ __launch_bounds__(256) void k_ctxred(const float* __restrict__ pctx,
                                                const float* __restrict__ smp,
                                                float* __restrict__ ctx) {
    const int b = blockIdx.x, t = threadIdx.x;
    const int h = b >> 5;                          // 32 blocks per head
    const int col = t & 63, ch = t >> 6;           // ch = chunk quarter
    __shared__ float sInv;
    __shared__ float psum[4][64];
    const size_t idx = (size_t)b * 64 + col;
    const int c0 = ch * 64;
    float s = 0.f;
#pragma unroll 16
    for (int c = 0; c < 64; ++c)
        s += __builtin_nontemporal_load(&pctx[(size_t)(c0 + c) * (NH * DIM) + idx]);
    psum[ch][col] = s;
    if (t < 32) {
        float v = smp[h * 32 + t];
        for (int off = 16; off; off >>= 1) v += __shfl_xor(v, off);
        if (t == 0) sInv = 1.0f / v;
    }
    __syncthreads();
    if (ch == 0)
        ctx[idx] = (psum[0][col] + psum[1][col] + psum[2][col] + psum[3][col]) * sInv;
}

// x1[row] = ctx[row>>7]·W_v[row] + b_kv[DIM+row]; one wave/row, 4 rows/block
__global__ __launch_bounds__(256) void k_x1(const float* __restrict__ Wkv,
                                            const float* __restrict__ bkv,
                                            const float* __restrict__ ctx,
                                            float* __restrict__ x1) {
    int row = blockIdx.x * 4 + (threadIdx.x >> 6);
    int lane = threadIdx.x & 63;
    const float* w = Wkv + (size_t)(DIM + row) * DIM;
    const float* c = ctx + (row >> 7) * DIM;
    float acc = 0.f;
#pragma unroll
    for (int k = 0; k < 8; ++k) {
        int j = k * 256 + lane * 4;
        f32x4 wv = __builtin_nontemporal_load((const f32x4*)&w[j]);
        f32x4 cv = *(const f32x4*)&c[j];
        acc += wv[0]*cv[0] + wv[1]*cv[1] + wv[2]*cv[2] + wv[3]*cv[3];
    }
    for (int off = 32; off; off >>= 1) acc += __shfl_xor(acc, off);
    if (lane == 0) x1[row] = acc + bkv[DIM + row];
}

// h1raw[row] = x1·W_p1[row] + b_p1[row]
__global__ __launch_bounds__(256) void k_h1(const float* __restrict__ Wp1,
                                            const float* __restrict__ bp1,
                                            const float* __restrict__ x1,
                                            float* __restrict__ h1raw) {
    int row = blockIdx.x * 4 + (threadIdx.x >> 6);
    int lane = threadIdx.x & 63;
    const float* w = Wp1 + (size_t)row * DIM;
    float acc = 0.f;
#pragma unroll
    for (int k = 0; k < 8; ++k) {
        int j = k * 256 + lane * 4;
        f32x4 wv = __builtin_nontemporal_load((const f32x4*)&w[j]);
        f32x4 cv = *(const f32x4*)&x1[j];
        acc += wv[0]*cv[0] + wv[1]*cv[1] + wv[2]*cv[2] + wv[3]*cv[3];
    }
    for (int off = 32; off; off >>= 1) acc += __shfl_xor(acc, off);
    if (lane == 0) h1raw[row] = acc + bp1[row];
}

// Fused LN+relu+proj2: x1f[row] = relu(LN(h1raw))·W_p2[row] + b_p2[row]
__global__ __launch_bounds__(256) void k_x1f(const float* __restrict__ Wp2,
                                             const float* __restrict__ bp2,
                                             const float* __restrict__ h1raw,
                                             const float* __restrict__ lnw,
                                             const float* __restrict__ lnb,
                                             float* __restrict__ x1f) {
    int row = blockIdx.x * 4 + (threadIdx.x >> 6);
    int lane = threadIdx.x & 63;
    int j = lane * 8;
    float4 va = *(const float4*)&h1raw[j];
    float4 vb = *(const float4*)&h1raw[j + 4];
    float s = va.x + va.y + va.z + va.w + vb.x + vb.y + vb.z + vb.w;
    for (int off = 32; off; off >>= 1) s += __shfl_xor(s, off);
    float mu = s * (1.0f / PD);
    float dx[8];
    dx[0]=va.x-mu; dx[1]=va.y-mu; dx[2]=va.z-mu; dx[3]=va.w-mu;
    dx[4]=vb.x-mu; dx[5]=vb.y-mu; dx[6]=vb.z-mu; dx[7]=vb.w-mu;
    float s2 = 0.f;
#pragma unroll
    for (int i = 0; i < 8; ++i) s2 += dx[i] * dx[i];
    for (int off = 32; off; off >>= 1) s2 += __shfl_xor(s2, off);
    float rstd = rsqrtf(s2 * (1.0f / PD) + LN_EPS);
    float4 lw0 = *(const float4*)&lnw[j], lw1 = *(const float4*)&lnw[j + 4];
    float4 lb0 = *(const float4*)&lnb[j], lb1 = *(const float4*)&lnb[j + 4];
    float hln[8];
    hln[0]=fmaxf(dx[0]*rstd*lw0.x+lb0.x,0.f); hln[1]=fmaxf(dx[1]*rstd*lw0.y+lb0.y,0.f);
    hln[2]=fmaxf(dx[2]*rstd*lw0.z+lb0.z,0.f); hln[3]=fmaxf(dx[3]*rstd*lw0.w+lb0.w,0.f);
    hln[4]=fmaxf(dx[4]*rstd*lw1.x+lb1.x,0.f); hln[5]=fmaxf(dx[5]*rstd*lw1.y+lb1.y,0.f);
    hln[6]=fmaxf(dx[6]*rstd*lw1.z+lb1.z,0.f); hln[7]=fmaxf(dx[7]*rstd*lw1.w+lb1.w,0.f);
    const float* w = Wp2 + (size_t)row * PD + j;
    f32x4 w0 = __builtin_nontemporal_load((const f32x4*)w);
    f32x4 w1 = __builtin_nontemporal_load((const f32x4*)(w + 4));
    float acc = w0[0]*hln[0] + w0[1]*hln[1] + w0[2]*hln[2] + w0[3]*hln[3]
              + w1[0]*hln[4] + w1[1]*hln[5] + w1[2]*hln[6] + w1[3]*hln[7];
    for (int off = 32; off; off >>= 1) acc += __shfl_xor(acc, off);
    if (lane == 0) x1f[row] = acc + bp2[row];
}

// out[s][j] = x[s][j] + x1f[j]; 2 float4/thread, NT stores (write-once)
__global__ __launch_bounds__(256) void k_out(const float* __restrict__ x,
                                             const float* __restrict__ x1f,
                                             float* __restrict__ out) {
    size_t i = (size_t)blockIdx.x * 512 + threadIdx.x;
    f32x4 xv = ((const f32x4*)x)[i];
    f32x4 a  = ((const f32x4*)x1f)[(int)(i & 511)];
    __builtin_nontemporal_store(xv + a, (f32x4*)out + i);
    size_t i2 = i + 256;
    f32x4 xv2 = ((const f32x4*)x)[i2];
    f32x4 a2  = ((const f32x4*)x1f)[(int)(i2 & 511)];
    __builtin_nontemporal_store(xv2 + a2, (f32x4*)out + i2);
}

extern "C" void kernel_launch(void* const* d_in, const int* in_sizes, int n_in,
                              void* d_out, int out_size, void* d_ws, size_t ws_size,
                              hipStream_t stream) {
    const float* x    = (const float*)d_in[0];
    const float* q    = (const float*)d_in[1];
    const float* Wkv  = (const float*)d_in[2];
    const float* bkv  = (const float*)d_in[3];
    const float* Wp1  = (const float*)d_in[4];
    const float* bp1  = (const float*)d_in[5];
    const float* Wp2  = (const float*)d_in[6];
    const float* bp2  = (const float*)d_in[7];
    const float* lnw  = (const float*)d_in[8];
    const float* lnb  = (const float*)d_in[9];
    float* out = (float*)d_out;
    float* ws  = (float*)d_ws;

    float*  qb    = ws + OFF_QB;
    float*  smp   = ws + OFF_SMP;
    __bf16* qWb   = (__bf16*)(ws + OFF_QWB);
    float*  pctx  = ws + OFF_PCTX;
    float*  ctx   = ws + OFF_CTX;
    float*  x1    = ws + OFF_X1;
    float*  h1raw = ws + OFF_H1R;
    float*  x1f   = ws + OFF_X1F;

    k_prep  <<<256, 256, 0, stream>>>(q, Wkv, bkv, qWb, qb, smp);
    k_fctx  <<<256, 512, 0, stream>>>(x, qWb, qb, pctx, smp);
    k_ctxred<<<512, 256, 0, stream>>>(pctx, smp, ctx);
    k_x1    <<<512, 256, 0, stream>>>(Wkv, bkv, ctx, x1);
    k_h1    <<<128, 256, 0, stream>>>(Wp1, bp1, x1, h1raw);
    k_x1f   <<<512, 256, 0, stream>>>(Wp2, bp2, h1raw, lnw, lnb, x1f);
    k_out   <<<8192, 256, 0, stream>>>(x, x1f, out);
}

// Round 9
// 204.146 us; speedup vs baseline: 1.5435x; 1.0127x over previous
//
#include <hip/hip_runtime.h>
#include <math.h>

#define SEQ   8192
#define DIM   2048
#define NH    16
#define DH    128
#define PD    512

static constexpr float LN_EPS = 1e-5f;
static constexpr float SCALE  = 0.08838834764831845f; // 1/sqrt(128)

typedef __bf16 bf16x8 __attribute__((ext_vector_type(8)));
typedef float  f32x4  __attribute__((ext_vector_type(4)));

// ---- workspace layout (floats); all offsets 16B aligned ----
static constexpr size_t OFF_QB   = 0;                    // 16
static constexpr size_t OFF_SMP  = 16;                   // 512 = smp[h][32]
static constexpr size_t OFF_QWB  = 528;                  // 16*2048 bf16 = 16384 floats
static constexpr size_t OFF_PCTX = 16912;                // 256*16*2048 = 8388608
static constexpr size_t OFF_CTX  = OFF_PCTX + 8388608;   // 32768
static constexpr size_t OFF_X1   = OFF_CTX + 32768;      // 2048
static constexpr size_t OFF_H1R  = OFF_X1 + 2048;        // 512
static constexpr size_t OFF_X1F  = OFF_H1R + 512;        // 2048

// async 16B global->LDS DMA; tracked by vmcnt (not lgkm).
__device__ __forceinline__ void gload_lds16(const float* g, float* l) {
    __builtin_amdgcn_global_load_lds(
        (const __attribute__((address_space(1))) uint32_t*)g,
        (__attribute__((address_space(3))) uint32_t*)l,
        16, 0, 0);
}

// Raw barrier: drain LDS ops only -- vmcnt (prefetch DMAs) stays in flight.
// __syncthreads() would emit s_waitcnt vmcnt(0) and kill the pipeline.
#define LBAR() do {                                        \
    asm volatile("s_waitcnt lgkmcnt(0)" ::: "memory");     \
    __builtin_amdgcn_s_barrier();                          \
} while (0)

// qWb[h][j] = bf16( q_h · W_k[:,j] ), qb[h] = q_h · b_k[h]; zero smp.
// grid 256 = (h 16) x (jc 16); 256 thr: col = t&127, k-half = t>>7
__global__ __launch_bounds__(256) void k_prep(const float* __restrict__ q,
                                              const float* __restrict__ Wkv,
                                              const float* __restrict__ bkv,
                                              __bf16* __restrict__ qWb,
                                              float* __restrict__ qb,
                                              float* __restrict__ smp) {
    int t = threadIdx.x;
    int h = blockIdx.x >> 4, jc = blockIdx.x & 15;
    int col = t & 127, kh = t >> 7;
    int j = jc * 128 + col;
    const float* w  = Wkv + (size_t)(h * DH + kh * 64) * DIM + j;
    const float* qh = q + h * DH + kh * 64;
    float acc = 0.f;
#pragma unroll 16
    for (int d = 0; d < 64; ++d)
        acc += qh[d] * __builtin_nontemporal_load(w + (size_t)d * DIM);
    __shared__ float part[128];
    if (kh) part[col] = acc;
    __syncthreads();
    if (!kh) qWb[h * DIM + j] = (__bf16)(acc + part[col]);
    if (jc == 0 && t < 64) {
        float p = q[h*DH + t] * bkv[h*DH + t] + q[h*DH + 64 + t] * bkv[h*DH + 64 + t];
        for (int off = 32; off; off >>= 1) p += __shfl_down(p, off);
        if (t == 0) qb[h] = p;
    }
    if (blockIdx.x == 0) { smp[t] = 0.f; smp[t + 256] = 0.f; }
}

// Fused logits+ctx, ROUND-9: DOUBLE-BUFFERED 8-row DMA pipeline.
// Rounds 3-8 all ~40us at 2.3-2.5 TB/s: staging was SERIAL with compute
// (vmcnt(0)+__syncthreads drained everything each phase). Fix = T3/T4:
// counted vmcnt(8) + raw s_barrier (lgkm-only), stage s+1 in flight across
// the whole compute of stage s. qWb B-frags hoisted to regs ONCE (stage-
// invariant) so the loop's only vmem ops are the DMAs -> vmcnt FIFO clean.
// MFMA runs half-filled (8 rows, r&7 dup) -- MfmaUtil is 0.4%, don't care.
#define ROWF 2052   // 2048 + 4 pad floats
__global__ __launch_bounds__(512) void k_fctx(const float* __restrict__ x,
                                              const __bf16* __restrict__ qWb,
                                              const float* __restrict__ qb,
                                              float* __restrict__ pctx,
                                              float* __restrict__ smp) {
    const int b = blockIdx.x, t = threadIdx.x;
    const int w8 = t >> 6, lane = t & 63;
    const int s0 = b * 32;
    const int r = lane & 15, quad = lane >> 4;

    __shared__ float buf[2][8 * ROWF];      // 2 x 65,664 B
    __shared__ float dpart[8][64][4];       // 8 KB
    __shared__ float att[8][NH];            // 512 B
    __shared__ float hsum[NH];
    if (t < NH) hsum[t] = 0.f;

    const int kbase = w8 * 256;             // this wave's K-eighth (256 cols)
    const int j0 = t * 4;                   // phase-B column

    // Hoist B-operand: same qWb fragments for all 4 stages (8 x 16B).
    bf16x8 BV[8];
    {
        const __bf16* brow = qWb + r * DIM + kbase + quad * 8;
#pragma unroll
        for (int i = 0; i < 8; ++i) BV[i] = *(const bf16x8*)(brow + i * 32);
    }

    f32x4 acc4[NH];
#pragma unroll
    for (int h = 0; h < NH; ++h) acc4[h] = (f32x4){0.f, 0.f, 0.f, 0.f};

    // prologue: stage 0 (8 DMAs/wave: 8 rows x own 1KB column slice)
    {
        const float* gsrc = x + (size_t)s0 * DIM + kbase + lane * 4;
        float*       ldst = &buf[0][0] + kbase + lane * 4;
#pragma unroll
        for (int i = 0; i < 8; ++i)
            gload_lds16(gsrc + (size_t)i * DIM, ldst + i * ROWF);
    }

#pragma unroll
    for (int s = 0; s < 4; ++s) {
        float* cbuf = &buf[s & 1][0];
        // issue next stage, then wait ONLY for current (8 newest stay in flight)
        if (s < 3) {
            const float* gsrc = x + (size_t)(s0 + (s + 1) * 8) * DIM + kbase + lane * 4;
            float*       ldst = &buf[(s + 1) & 1][0] + kbase + lane * 4;
#pragma unroll
            for (int i = 0; i < 8; ++i)
                gload_lds16(gsrc + (size_t)i * DIM, ldst + i * ROWF);
            asm volatile("s_waitcnt vmcnt(8)" ::: "memory");
        } else {
            asm volatile("s_waitcnt vmcnt(0)" ::: "memory");
        }

        // phase A: MFMA logit partials over this wave's OWN staged columns
        // (no barrier needed: vmcnt(8) covers exactly these LDS writes)
        {
            const float* lrow = cbuf + (r & 7) * ROWF + kbase + quad * 8;
            f32x4 acc = {0.f, 0.f, 0.f, 0.f};
#pragma unroll
            for (int i = 0; i < 8; ++i) {
                f32x4 xa = *(const f32x4*)(lrow + i * 32);
                f32x4 xb = *(const f32x4*)(lrow + i * 32 + 4);
                bf16x8 af;
                af[0] = (__bf16)xa[0]; af[1] = (__bf16)xa[1];
                af[2] = (__bf16)xa[2]; af[3] = (__bf16)xa[3];
                af[4] = (__bf16)xb[0]; af[5] = (__bf16)xb[1];
                af[6] = (__bf16)xb[2]; af[7] = (__bf16)xb[3];
                acc = __builtin_amdgcn_mfma_f32_16x16x32_bf16(af, BV[i], acc, 0, 0, 0);
            }
            *(f32x4*)&dpart[w8][lane][0] = acc;
        }
        LBAR();   // dpart visible; also: every wave passed its vmcnt -> stage-s
                  // data from ALL waves now visible (needed by phase B)

        // combine 8 K-eighths -> e for the 8 rows of this stage
        if (t < 128) {
            const int h = t & 15, sl = t >> 4;          // sl = 0..7
            const int quad2 = sl >> 2, reg2 = sl & 3;
            const int lane2 = quad2 * 16 + h;
            float v = 0.f;
#pragma unroll
            for (int kk = 0; kk < 8; ++kk) v += dpart[kk][lane2][reg2];
            float e = __expf((v + qb[h]) * SCALE);      // |logit*SCALE| <~ 5
            att[sl][h] = e;
            atomicAdd(&hsum[h], e);
        }
        LBAR();   // att ready

        // phase B: acc4[h] += e[rr][h] * x[rr][j0..j0+4) from LDS
#pragma unroll 2
        for (int rr = 0; rr < 8; ++rr) {
            f32x4 xv = *(const f32x4*)(cbuf + rr * ROWF + j0);
            const f32x4* ar = (const f32x4*)att[rr];    // 64B broadcast
            f32x4 a0 = ar[0], a1 = ar[1], a2 = ar[2], a3 = ar[3];
            float aa[16];
            *(f32x4*)&aa[0] = a0; *(f32x4*)&aa[4]  = a1;
            *(f32x4*)&aa[8] = a2; *(f32x4*)&aa[12] = a3;
#pragma unroll
            for (int h = 0; h < NH; ++h) acc4[h] += xv * aa[h];
        }
        LBAR();   // buf[s&1] free for stage s+2's DMAs (issued next iter)
    }

    if (t < NH) atomicAdd(&smp[t * 32 + (b & 31)], hsum[t]);
    // NT stores: pctx write-once/read-once; keep L2 clean.
#pragma unroll
    for (int h = 0; h < NH; ++h)
        __builtin_nontemporal_store(acc4[h],
            (f32x4*)&pctx[((size_t)(b * NH + h)) * DIM + j0]);
}
#undef ROWF

// ctx[idx] = (sum_{c<256} pctx[c][idx]) / S[head(idx)]
// grid 512; each block owns 64 outputs; 4-way chunk-split + LDS combine.
__global__ __launch_bounds__(256) void k_ctxred(const float* __restrict__ pctx,
                                                const float* __restrict__ smp,
                                                float* __restrict__ ctx) {
    const int b = blockIdx.x, t = threadIdx.x;
    const int h = b >> 5;                          // 32 blocks per head
    const int col = t & 63, ch = t >> 6;           // ch = chunk quarter
    __shared__ float sInv;
    __shared__ float psum[4][64];
    const size_t idx = (size_t)b * 64 + col;
    const int c0 = ch * 64;
    float s = 0.f;
#pragma unroll 16
    for (int c = 0; c < 64; ++c)
        s += __builtin_nontemporal_load(&pctx[(size_t)(c0 + c) * (NH * DIM) + idx]);
    psum[ch][col] = s;
    if (t < 32) {
        float v = smp[h * 32 + t];
        for (int off = 16; off; off >>= 1) v += __shfl_xor(v, off);
        if (t == 0) sInv = 1.0f / v;
    }
    __syncthreads();
    if (ch == 0)
        ctx[idx] = (psum[0][col] + psum[1][col] + psum[2][col] + psum[3][col]) * sInv;
}

// x1[row] = ctx[row>>7]·W_v[row] + b_kv[DIM+row]; one wave/row, 4 rows/block
__global__ __launch_bounds__(256) void k_x1(const float* __restrict__ Wkv,
                                            const float* __restrict__ bkv,
                                            const float* __restrict__ ctx,
                                            float* __restrict__ x1) {
    int row = blockIdx.x * 4 + (threadIdx.x >> 6);
    int lane = threadIdx.x & 63;
    const float* w = Wkv + (size_t)(DIM + row) * DIM;
    const float* c = ctx + (row >> 7) * DIM;
    float acc = 0.f;
#pragma unroll
    for (int k = 0; k < 8; ++k) {
        int j = k * 256 + lane * 4;
        f32x4 wv = __builtin_nontemporal_load((const f32x4*)&w[j]);
        f32x4 cv = *(const f32x4*)&c[j];
        acc += wv[0]*cv[0] + wv[1]*cv[1] + wv[2]*cv[2] + wv[3]*cv[3];
    }
    for (int off = 32; off; off >>= 1) acc += __shfl_xor(acc, off);
    if (lane == 0) x1[row] = acc + bkv[DIM + row];
}

// h1raw[row] = x1·W_p1[row] + b_p1[row]
__global__ __launch_bounds__(256) void k_h1(const float* __restrict__ Wp1,
                                            const float* __restrict__ bp1,
                                            const float* __restrict__ x1,
                                            float* __restrict__ h1raw) {
    int row = blockIdx.x * 4 + (threadIdx.x >> 6);
    int lane = threadIdx.x & 63;
    const float* w = Wp1 + (size_t)row * DIM;
    float acc = 0.f;
#pragma unroll
    for (int k = 0; k < 8; ++k) {
        int j = k * 256 + lane * 4;
        f32x4 wv = __builtin_nontemporal_load((const f32x4*)&w[j]);
        f32x4 cv = *(const f32x4*)&x1[j];
        acc += wv[0]*cv[0] + wv[1]*cv[1] + wv[2]*cv[2] + wv[3]*cv[3];
    }
    for (int off = 32; off; off >>= 1) acc += __shfl_xor(acc, off);
    if (lane == 0) h1raw[row] = acc + bp1[row];
}

// Fused LN+relu+proj2: x1f[row] = relu(LN(h1raw))·W_p2[row] + b_p2[row]
__global__ __launch_bounds__(256) void k_x1f(const float* __restrict__ Wp2,
                                             const float* __restrict__ bp2,
                                             const float* __restrict__ h1raw,
                                             const float* __restrict__ lnw,
                                             const float* __restrict__ lnb,
                                             float* __restrict__ x1f) {
    int row = blockIdx.x * 4 + (threadIdx.x >> 6);
    int lane = threadIdx.x & 63;
    int j = lane * 8;
    float4 va = *(const float4*)&h1raw[j];
    float4 vb = *(const float4*)&h1raw[j + 4];
    float s = va.x + va.y + va.z + va.w + vb.x + vb.y + vb.z + vb.w;
    for (int off = 32; off; off >>= 1) s += __shfl_xor(s, off);
    float mu = s * (1.0f / PD);
    float dx[8];
    dx[0]=va.x-mu; dx[1]=va.y-mu; dx[2]=va.z-mu; dx[3]=va.w-mu;
    dx[4]=vb.x-mu; dx[5]=vb.y-mu; dx[6]=vb.z-mu; dx[7]=vb.w-mu;
    float s2 = 0.f;
#pragma unroll
    for (int i = 0; i < 8; ++i) s2 += dx[i] * dx[i];
    for (int off = 32; off; off >>= 1) s2 += __shfl_xor(s2, off);
    float rstd = rsqrtf(s2 * (1.0f / PD) + LN_EPS);
    float4 lw0 = *(const float4*)&lnw[j], lw1 = *(const float4*)&lnw[j + 4];
    float4 lb0 = *(const float4*)&lnb[j], lb1 = *(const float4*)&lnb[j + 4];
    float hln[8];
    hln[0]=fmaxf(dx[0]*rstd*lw0.x+lb0.x,0.f); hln[1]=fmaxf(dx[1]*rstd*lw0.y+lb0.y,0.f);
    hln[2]=fmaxf(dx[2]*rstd*lw0.z+lb0.z,0.f); hln[3]=fmaxf(dx[3]*rstd*lw0.w+lb0.w,0.f);
    hln[4]=fmaxf(dx[4]*rstd*lw1.x+lb1.x,0.f); hln[5]=fmaxf(dx[5]*rstd*lw1.y+lb1.y,0.f);
    hln[6]=fmaxf(dx[6]*rstd*lw1.z+lb1.z,0.f); hln[7]=fmaxf(dx[7]*rstd*lw1.w+lb1.w,0.f);
    const float* w = Wp2 + (size_t)row * PD + j;
    f32x4 w0 = __builtin_nontemporal_load((const f32x4*)w);
    f32x4 w1 = __builtin_nontemporal_load((const f32x4*)(w + 4));
    float acc = w0[0]*hln[0] + w0[1]*hln[1] + w0[2]*hln[2] + w0[3]*hln[3]
              + w1[0]*hln[4] + w1[1]*hln[5] + w1[2]*hln[6] + w1[3]*hln[7];
    for (int off = 32; off; off >>= 1) acc += __shfl_xor(acc, off);
    if (lane == 0) x1f[row] = acc + bp2[row];
}

// out[s][j] = x[s][j] + x1f[j]; 2 float4/thread, NT stores (write-once)
__global__ __launch_bounds__(256) void k_out(const float* __restrict__ x,
                                             const float* __restrict__ x1f,
                                             float* __restrict__ out) {
    size_t i = (size_t)blockIdx.x * 512 + threadIdx.x;
    f32x4 xv = ((const f32x4*)x)[i];
    f32x4 a  = ((const f32x4*)x1f)[(int)(i & 511)];
    __builtin_nontemporal_store(xv + a, (f32x4*)out + i);
    size_t i2 = i + 256;
    f32x4 xv2 = ((const f32x4*)x)[i2];
    f32x4 a2  = ((const f32x4*)x1f)[(int)(i2 & 511)];
    __builtin_nontemporal_store(xv2 + a2, (f32x4*)out + i2);
}

extern "C" void kernel_launch(void* const* d_in, const int* in_sizes, int n_in,
                              void* d_out, int out_size, void* d_ws, size_t ws_size,
                              hipStream_t stream) {
    const float* x    = (const float*)d_in[0];
    const float* q    = (const float*)d_in[1];
    const float* Wkv  = (const float*)d_in[2];
    const float* bkv  = (const float*)d_in[3];
    const float* Wp1  = (const float*)d_in[4];
    const float* bp1  = (const float*)d_in[5];
    const float* Wp2  = (const float*)d_in[6];
    const float* bp2  = (const float*)d_in[7];
    const float* lnw  = (const float*)d_in[8];
    const float* lnb  = (const float*)d_in[9];
    float* out = (float*)d_out;
    float* ws  = (float*)d_ws;

    float*  qb    = ws + OFF_QB;
    float*  smp   = ws + OFF_SMP;
    __bf16* qWb   = (__bf16*)(ws + OFF_QWB);
    float*  pctx  = ws + OFF_PCTX;
    float*  ctx   = ws + OFF_CTX;
    float*  x1    = ws + OFF_X1;
    float*  h1raw = ws + OFF_H1R;
    float*  x1f   = ws + OFF_X1F;

    k_prep  <<<256, 256, 0, stream>>>(q, Wkv, bkv, qWb, qb, smp);
    k_fctx  <<<256, 512, 0, stream>>>(x, qWb, qb, pctx, smp);
    k_ctxred<<<512, 256, 0, stream>>>(pctx, smp, ctx);
    k_x1    <<<512, 256, 0, stream>>>(Wkv, bkv, ctx, x1);
    k_h1    <<<128, 256, 0, stream>>>(Wp1, bp1, x1, h1raw);
    k_x1f   <<<512, 256, 0, stream>>>(Wp2, bp2, h1raw, lnw, lnb, x1f);
    k_out   <<<8192, 256, 0, stream>>>(x, x1f, out);
}